// Round 16
// baseline (211.086 us; speedup 1.0000x reference)
//
#include <hip/hip_runtime.h>
#include <math.h>

#define BB 4
#define TT 2048
#define EE 384
#define HH 6
#define DD 64
#define MM (BB*TT)   // 8192 tokens

typedef __attribute__((ext_vector_type(8))) short bf16x8;
typedef __attribute__((ext_vector_type(4))) float f32x4;

__device__ __forceinline__ unsigned short f2bf(float f) {
    unsigned int u = __float_as_uint(f);
    u = (u + 0x7FFFu + ((u >> 16) & 1u)) >> 16;   // RNE
    return (unsigned short)u;
}
__device__ __forceinline__ float bf2f(unsigned short u) {
    return __uint_as_float(((unsigned int)u) << 16);
}
__device__ __forceinline__ unsigned int pk2(float a, float b) {
    return (unsigned int)f2bf(a) | ((unsigned int)f2bf(b) << 16);
}

// ------------- fp32 -> bf16 conversion: x (3072 blocks) + 4 weights (144 each) -------
__global__ __launch_bounds__(256) void k_cvt(const float* __restrict__ x,
                                             const float* __restrict__ wq,
                                             const float* __restrict__ wo,
                                             const float* __restrict__ w1,
                                             const float* __restrict__ w2,
                                             unsigned short* __restrict__ xb,
                                             unsigned short* __restrict__ wqb,
                                             unsigned short* __restrict__ wob,
                                             unsigned short* __restrict__ w1b,
                                             unsigned short* __restrict__ w2b)
{
    int bid = blockIdx.x;
    const float* src; unsigned short* dst; int i;
    if (bid < 3072)       { src = x;  dst = xb;  i = bid * 256; }
    else {
        int r = bid - 3072, wi = r / 144, off = (r % 144) * 256;
        const float* s4[4] = {wq, wo, w1, w2};
        unsigned short* d4[4] = {wqb, wob, w1b, w2b};
        src = s4[wi]; dst = d4[wi]; i = off;
    }
    i += threadIdx.x;
    float4 v = ((const float4*)src)[i];
    uint2 o; o.x = pk2(v.x, v.y); o.y = pk2(v.z, v.w);
    ((uint2*)dst)[i] = o;
}

// ------------- q-GEMM: A bf16, writes qbf[b,h,t,d] bf16 ------------------------------
__global__ __launch_bounds__(256, 4) void k_qgemm(const unsigned short* __restrict__ A,
                                                  const unsigned short* __restrict__ W,
                                                  unsigned short* __restrict__ qbf)
{
    const int tid = threadIdx.x;
    const int w = tid >> 6, lane = tid & 63;
    const int fr = lane & 15, quad = lane >> 4;
    const int m0 = blockIdx.x * 16;
    const int n0 = blockIdx.y * 192 + w * 48;
    const unsigned short* Ap = A + (size_t)(m0 + fr) * EE + quad * 8;
    const unsigned short* Wp = W + (size_t)(n0 + fr) * EE + quad * 8;

    f32x4 acc[3];
    #pragma unroll
    for (int nt = 0; nt < 3; nt++) acc[nt] = (f32x4){0.f, 0.f, 0.f, 0.f};

    #pragma unroll
    for (int k0 = 0; k0 < 12; k0++) {
        bf16x8 a = *(const bf16x8*)(Ap + k0 * 32);
        #pragma unroll
        for (int nt = 0; nt < 3; nt++) {
            bf16x8 b = *(const bf16x8*)(Wp + (size_t)nt * 16 * EE + k0 * 32);
            acc[nt] = __builtin_amdgcn_mfma_f32_16x16x32_bf16(a, b, acc[nt], 0, 0, 0);
        }
    }

    const int mrow = m0 + quad * 4;
    #pragma unroll
    for (int nt = 0; nt < 3; nt++) {
        int n = n0 + nt * 16 + fr;
        int h = n >> 6, d = n & 63;
        #pragma unroll
        for (int r = 0; r < 4; r++) {
            int m = mrow + r;
            int b = m >> 11, t = m & 2047;
            qbf[((size_t)(b * HH + h) * TT + t) * DD + d] = f2bf(acc[nt][r]);
        }
    }
}

// ------------- transpose qbf[b,h,t,d] -> qbfT[b,h,d,t] (bf16, coalesced) -------------
__global__ __launch_bounds__(256) void k_prep(const unsigned short* __restrict__ qbf,
                                              unsigned short* __restrict__ qbfT)
{
    __shared__ unsigned short Ls[64][72];
    const int bh = blockIdx.y;
    const int t0 = blockIdx.x * 64;
    const unsigned short* src = qbf + ((size_t)bh * TT + t0) * DD;
    {
        int r = threadIdx.x >> 2, c = (threadIdx.x & 3) * 16;
        const unsigned short* p = src + (size_t)r * DD + c;
        *(uint4*)&Ls[r][c]     = *(const uint4*)(p);
        *(uint4*)&Ls[r][c + 8] = *(const uint4*)(p + 8);
    }
    __syncthreads();
    {
        int d = threadIdx.x >> 2, tc = (threadIdx.x & 3) * 16;
        unsigned short tmp[16];
        #pragma unroll
        for (int i = 0; i < 16; i++) tmp[i] = Ls[tc + i][d];
        unsigned short* dst = qbfT + ((size_t)bh * DD + d) * TT + t0 + tc;
        *(uint4*)(dst)     = *(const uint4*)&tmp[0];
        *(uint4*)(dst + 8) = *(const uint4*)&tmp[8];
    }
}

// ------------- MFMA flash attention: XCD swizzle + K/V LDS double-buffer -------------
// Single barrier per key-iteration: compute from buf[cur] while writing buf[cur^1]
// (which no wave reads this iteration); lockstep barrier at iter end. Oc (fp32 scratch
// used only post-loop, barrier-fenced) overlays Ks[0] so LDS stays 46.2 KB = 3 blk/CU.
__global__ __launch_bounds__(256, 4) void k_attn(const unsigned short* __restrict__ qbf,
                                                 const unsigned short* __restrict__ qbfT,
                                                 unsigned short* __restrict__ cat)
{
    __shared__ unsigned short Qs[32][72];
    __shared__ unsigned short Ks[2][64][72];
    __shared__ unsigned short Vs[2][64][72];
    __shared__ unsigned short Ps[32][72];
    __shared__ float lsc[32];
    float (*Oc)[68] = (float(*)[68])&Ks[0][0][0];   // overlay (8704 B <= 9216 B)

    const int id = blockIdx.x;              // 0..767
    const int xcd = id & 7, j = id >> 3;
    const int bh = xcd * 3 + (j % 3);       // XCD-affine: 3 heads per XCD
    const int p = j / 3;                    // 0..31
    const int bb = bh / HH, hh = bh % HH;
    const int tid = threadIdx.x;
    const int w = tid >> 6, lane = tid & 63;
    const int qhalf = w & 1, keyhalf = w >> 1;
    const int fr = lane & 15, quad = lane >> 4;
    const int fc = quad * 8;
    const unsigned short* qb  = qbf  + (size_t)bh * TT * DD;
    const unsigned short* qtb = qbfT + (size_t)bh * DD * TT;
    const int lr = tid >> 2, lc = (tid & 3) * 16;
    const int qr = tid >> 3, qc = (tid & 7) * 8;

    #pragma unroll 1
    for (int ph = 0; ph < 2; ph++) {
        const int tile = ph ? (63 - p) : p;
        const int m0 = tile * 32;
        const int nkt = (tile >> 1) + 1;

        // prefetch key-tile 0
        uint4 kr0, kr1, vr0, vr1;
        {
            const unsigned short* kp = qb + (size_t)lr * DD + lc;
            kr0 = *(const uint4*)(kp);
            kr1 = *(const uint4*)(kp + 8);
            const unsigned short* vp = qtb + (size_t)lr * TT + lc;
            vr0 = *(const uint4*)(vp);
            vr1 = *(const uint4*)(vp + 8);
        }

        __syncthreads();   // prev phase fully done (incl. Oc-overlay reads) before overwrite
        {
            const unsigned short* qp = qb + (size_t)(m0 + qr) * DD + qc;
            *(uint4*)&Qs[qr][qc] = *(const uint4*)(qp);
        }
        *(uint4*)&Ks[0][lr][lc]     = kr0;
        *(uint4*)&Ks[0][lr][lc + 8] = kr1;
        *(uint4*)&Vs[0][lr][lc]     = vr0;
        *(uint4*)&Vs[0][lr][lc + 8] = vr1;
        __syncthreads();   // Qs + buf0 visible
        const bf16x8 qA0 = *(const bf16x8*)&Qs[qhalf * 16 + fr][fc];
        const bf16x8 qA1 = *(const bf16x8*)&Qs[qhalf * 16 + fr][fc + 32];

        f32x4 accO[4];
        #pragma unroll
        for (int dt = 0; dt < 4; dt++) accO[dt] = (f32x4){0.f, 0.f, 0.f, 0.f};
        float ls[4] = {0.f, 0.f, 0.f, 0.f};
        const int rowbase = m0 + qhalf * 16 + quad * 4;
        const int prow = qhalf * 16 + quad * 4;

        for (int kt = 0; kt < nkt; kt++) {
            const int cur = kt & 1;
            const int s0 = kt * 64;
            if (kt < nkt - 1) {   // prefetch next tile into registers
                const unsigned short* kp = qb + (size_t)(s0 + 64 + lr) * DD + lc;
                kr0 = *(const uint4*)(kp);
                kr1 = *(const uint4*)(kp + 8);
                const unsigned short* vp = qtb + (size_t)lr * TT + s0 + 64 + lc;
                vr0 = *(const uint4*)(vp);
                vr1 = *(const uint4*)(vp + 8);
            }

            f32x4 S[2];
            #pragma unroll
            for (int nt = 0; nt < 2; nt++) {
                f32x4 acc = (f32x4){0.f, 0.f, 0.f, 0.f};
                bf16x8 b0 = *(const bf16x8*)&Ks[cur][keyhalf * 32 + nt * 16 + fr][fc];
                acc = __builtin_amdgcn_mfma_f32_16x16x32_bf16(qA0, b0, acc, 0, 0, 0);
                bf16x8 b1 = *(const bf16x8*)&Ks[cur][keyhalf * 32 + nt * 16 + fr][fc + 32];
                acc = __builtin_amdgcn_mfma_f32_16x16x32_bf16(qA1, b1, acc, 0, 0, 0);
                S[nt] = acc;
            }

            #pragma unroll
            for (int nt = 0; nt < 2; nt++) {
                int jg = s0 + keyhalf * 32 + nt * 16 + fr;
                #pragma unroll
                for (int r = 0; r < 4; r++) {
                    float v = S[nt][r] * 0.125f;
                    float pv = (jg <= rowbase + r && v != 0.0f) ? __expf(v) : 0.0f;
                    ls[r] += pv;
                    Ps[prow + r][keyhalf * 32 + nt * 16 + fr] = f2bf(pv);
                }
            }

            bf16x8 pA = *(const bf16x8*)&Ps[qhalf * 16 + fr][keyhalf * 32 + fc];
            #pragma unroll
            for (int dt = 0; dt < 4; dt++) {
                bf16x8 v0 = *(const bf16x8*)&Vs[cur][dt * 16 + fr][keyhalf * 32 + fc];
                accO[dt] = __builtin_amdgcn_mfma_f32_16x16x32_bf16(pA, v0, accO[dt], 0, 0, 0);
            }

            if (kt < nkt - 1) {   // stage next tile into the alternate buffer
                *(uint4*)&Ks[cur ^ 1][lr][lc]     = kr0;
                *(uint4*)&Ks[cur ^ 1][lr][lc + 8] = kr1;
                *(uint4*)&Vs[cur ^ 1][lr][lc]     = vr0;
                *(uint4*)&Vs[cur ^ 1][lr][lc + 8] = vr1;
                __syncthreads();   // single barrier per iteration
            }
        }

        __syncthreads();   // final-iter LDS reads complete before Oc-overlay write
        #pragma unroll
        for (int r = 0; r < 4; r++) {
            #pragma unroll
            for (int o = 1; o < 16; o <<= 1) ls[r] += __shfl_xor(ls[r], o, 64);
        }
        if (keyhalf == 1) {
            #pragma unroll
            for (int dt = 0; dt < 4; dt++)
                #pragma unroll
                for (int r = 0; r < 4; r++)
                    Oc[prow + r][dt * 16 + fr] = accO[dt][r];
            if (fr == 0) {
                #pragma unroll
                for (int r = 0; r < 4; r++) lsc[prow + r] = ls[r];
            }
        }
        __syncthreads();
        if (keyhalf == 0) {
            float lt[4];
            #pragma unroll
            for (int r = 0; r < 4; r++) lt[r] = ls[r] + lsc[prow + r];
            #pragma unroll
            for (int dt = 0; dt < 4; dt++) {
                #pragma unroll
                for (int r = 0; r < 4; r++) {
                    float o = accO[dt][r] + Oc[prow + r][dt * 16 + fr];
                    int t = rowbase + r;
                    cat[((size_t)bb * TT + t) * EE + hh * DD + dt * 16 + fr] =
                        f2bf(o / lt[r]);
                }
            }
        }
    }
}

// ------------- fused proj+LN1 + FFN1 + FFN2+LN2 --------------------------------------
// 512 threads, 16 rows/block, grid 512: 8 waves x 48n (3 acc), 2 blocks/CU = 16
// waves/CU. launch_bounds(512,2) caps VGPR at 256 so the b-frag double-buffer
// survives (R12's (512,4) strangled it to VGPR=36).
__global__ __launch_bounds__(512, 2) void k_ffn(const unsigned short* __restrict__ catb,
                                                const unsigned short* __restrict__ wob,
                                                const float* __restrict__ bo,
                                                const float* __restrict__ x,
                                                const float* __restrict__ g1,
                                                const float* __restrict__ be1,
                                                const unsigned short* __restrict__ w1b,
                                                const float* __restrict__ b1,
                                                const unsigned short* __restrict__ w2b,
                                                const float* __restrict__ b2,
                                                const float* __restrict__ g2,
                                                const float* __restrict__ be2,
                                                float* __restrict__ out)
{
    __shared__ unsigned short X1s[16][392];
    __shared__ unsigned short H1s[16][392];
    __shared__ float ssum[16][8];
    __shared__ float ssq[16][8];
    const int tid = threadIdx.x;
    const int w = tid >> 6, lane = tid & 63;
    const int fr = lane & 15, quad = lane >> 4;
    const int m0 = blockIdx.x * 16;
    const int n0 = w * 48;

    f32x4 acc[3];
    bf16x8 bc[3], bn[3];

    // ================= GEMM1: proj = catb @ Wo^T =================
    {
        const unsigned short* Ap = catb + (size_t)(m0 + fr) * EE + quad * 8;
        const unsigned short* Wp = wob + (size_t)(n0 + fr) * EE + quad * 8;
        #pragma unroll
        for (int nt = 0; nt < 3; nt++) acc[nt] = (f32x4){0.f, 0.f, 0.f, 0.f};
        #pragma unroll
        for (int nt = 0; nt < 3; nt++) bc[nt] = *(const bf16x8*)(Wp + (size_t)nt * 16 * EE);
        #pragma unroll
        for (int k0 = 0; k0 < 12; k0++) {
            if (k0 < 11) {
                #pragma unroll
                for (int nt = 0; nt < 3; nt++)
                    bn[nt] = *(const bf16x8*)(Wp + (size_t)nt * 16 * EE + (k0 + 1) * 32);
            }
            bf16x8 a = *(const bf16x8*)(Ap + k0 * 32);
            #pragma unroll
            for (int nt = 0; nt < 3; nt++)
                acc[nt] = __builtin_amdgcn_mfma_f32_16x16x32_bf16(a, bc[nt], acc[nt], 0, 0, 0);
            #pragma unroll
            for (int nt = 0; nt < 3; nt++) bc[nt] = bn[nt];
        }
    }
    // + bo + resid(x) -> LN1 stats
    {
        float s1[4] = {0.f, 0.f, 0.f, 0.f}, s2[4] = {0.f, 0.f, 0.f, 0.f};
        #pragma unroll
        for (int nt = 0; nt < 3; nt++) {
            int n = n0 + nt * 16 + fr;
            float bv = bo[n];
            #pragma unroll
            for (int r = 0; r < 4; r++) {
                float v = acc[nt][r] + bv + x[(size_t)(m0 + quad * 4 + r) * EE + n];
                acc[nt][r] = v;
                s1[r] += v;
                s2[r] += v * v;
            }
        }
        #pragma unroll
        for (int r = 0; r < 4; r++) {
            #pragma unroll
            for (int o = 1; o < 16; o <<= 1) {
                s1[r] += __shfl_xor(s1[r], o, 64);
                s2[r] += __shfl_xor(s2[r], o, 64);
            }
        }
        if (fr == 0) {
            #pragma unroll
            for (int r = 0; r < 4; r++) {
                ssum[quad * 4 + r][w] = s1[r];
                ssq [quad * 4 + r][w] = s2[r];
            }
        }
    }
    __syncthreads();
    {
        float mu[4], rs[4];
        #pragma unroll
        for (int r = 0; r < 4; r++) {
            int row = quad * 4 + r;
            float t1 = 0.f, t2 = 0.f;
            #pragma unroll
            for (int q = 0; q < 8; q++) { t1 += ssum[row][q]; t2 += ssq[row][q]; }
            mu[r] = t1 * (1.0f / EE);
            float var = t2 * (1.0f / EE) - mu[r] * mu[r];
            rs[r] = rsqrtf(var + 1e-5f);
        }
        #pragma unroll
        for (int nt = 0; nt < 3; nt++) {
            int n = n0 + nt * 16 + fr;
            float gv = g1[n], bev = be1[n];
            #pragma unroll
            for (int r = 0; r < 4; r++) {
                float v = (acc[nt][r] - mu[r]) * rs[r] * gv + bev;
                X1s[quad * 4 + r][n] = f2bf(v);
            }
        }
    }
    __syncthreads();

    // ================= GEMM2: h1 = relu(x1 @ W1^T + b1) =================
    {
        const unsigned short* Wp = w1b + (size_t)(n0 + fr) * EE + quad * 8;
        #pragma unroll
        for (int nt = 0; nt < 3; nt++) acc[nt] = (f32x4){0.f, 0.f, 0.f, 0.f};
        #pragma unroll
        for (int nt = 0; nt < 3; nt++) bc[nt] = *(const bf16x8*)(Wp + (size_t)nt * 16 * EE);
        #pragma unroll
        for (int k0 = 0; k0 < 12; k0++) {
            if (k0 < 11) {
                #pragma unroll
                for (int nt = 0; nt < 3; nt++)
                    bn[nt] = *(const bf16x8*)(Wp + (size_t)nt * 16 * EE + (k0 + 1) * 32);
            }
            bf16x8 a = *(const bf16x8*)&X1s[fr][k0 * 32 + quad * 8];
            #pragma unroll
            for (int nt = 0; nt < 3; nt++)
                acc[nt] = __builtin_amdgcn_mfma_f32_16x16x32_bf16(a, bc[nt], acc[nt], 0, 0, 0);
            #pragma unroll
            for (int nt = 0; nt < 3; nt++) bc[nt] = bn[nt];
        }
        #pragma unroll
        for (int nt = 0; nt < 3; nt++) {
            int n = n0 + nt * 16 + fr;
            float bv = b1[n];
            #pragma unroll
            for (int r = 0; r < 4; r++)
                H1s[quad * 4 + r][n] = f2bf(fmaxf(acc[nt][r] + bv, 0.0f));
        }
    }
    __syncthreads();

    // ================= GEMM3: ff = h1 @ W2^T + b2; LN2(x1 + ff) -> out =================
    {
        const unsigned short* Wp = w2b + (size_t)(n0 + fr) * EE + quad * 8;
        #pragma unroll
        for (int nt = 0; nt < 3; nt++) acc[nt] = (f32x4){0.f, 0.f, 0.f, 0.f};
        #pragma unroll
        for (int nt = 0; nt < 3; nt++) bc[nt] = *(const bf16x8*)(Wp + (size_t)nt * 16 * EE);
        #pragma unroll
        for (int k0 = 0; k0 < 12; k0++) {
            if (k0 < 11) {
                #pragma unroll
                for (int nt = 0; nt < 3; nt++)
                    bn[nt] = *(const bf16x8*)(Wp + (size_t)nt * 16 * EE + (k0 + 1) * 32);
            }
            bf16x8 a = *(const bf16x8*)&H1s[fr][k0 * 32 + quad * 8];
            #pragma unroll
            for (int nt = 0; nt < 3; nt++)
                acc[nt] = __builtin_amdgcn_mfma_f32_16x16x32_bf16(a, bc[nt], acc[nt], 0, 0, 0);
            #pragma unroll
            for (int nt = 0; nt < 3; nt++) bc[nt] = bn[nt];
        }
    }
    {
        float s1[4] = {0.f, 0.f, 0.f, 0.f}, s2[4] = {0.f, 0.f, 0.f, 0.f};
        #pragma unroll
        for (int nt = 0; nt < 3; nt++) {
            int n = n0 + nt * 16 + fr;
            float bv = b2[n];
            #pragma unroll
            for (int r = 0; r < 4; r++) {
                float v = acc[nt][r] + bv + bf2f(X1s[quad * 4 + r][n]);
                acc[nt][r] = v;
                s1[r] += v;
                s2[r] += v * v;
            }
        }
        #pragma unroll
        for (int r = 0; r < 4; r++) {
            #pragma unroll
            for (int o = 1; o < 16; o <<= 1) {
                s1[r] += __shfl_xor(s1[r], o, 64);
                s2[r] += __shfl_xor(s2[r], o, 64);
            }
        }
        if (fr == 0) {
            #pragma unroll
            for (int r = 0; r < 4; r++) {
                ssum[quad * 4 + r][w] = s1[r];
                ssq [quad * 4 + r][w] = s2[r];
            }
        }
    }
    __syncthreads();
    {
        float mu[4], rs[4];
        #pragma unroll
        for (int r = 0; r < 4; r++) {
            int row = quad * 4 + r;
            float u1 = 0.f, u2 = 0.f;
            #pragma unroll
            for (int q = 0; q < 8; q++) { u1 += ssum[row][q]; u2 += ssq[row][q]; }
            mu[r] = u1 * (1.0f / EE);
            float var = u2 * (1.0f / EE) - mu[r] * mu[r];
            rs[r] = rsqrtf(var + 1e-5f);
        }
        #pragma unroll
        for (int nt = 0; nt < 3; nt++) {
            int n = n0 + nt * 16 + fr;
            float gv = g2[n], bev = be2[n];
            #pragma unroll
            for (int r = 0; r < 4; r++)
                out[(size_t)(m0 + quad * 4 + r) * EE + n] =
                    (acc[nt][r] - mu[r]) * rs[r] * gv + bev;
        }
    }
}

extern "C" void kernel_launch(void* const* d_in, const int* in_sizes, int n_in,
                              void* d_out, int out_size, void* d_ws, size_t ws_size,
                              hipStream_t stream) {
    (void)in_sizes; (void)n_in; (void)out_size; (void)ws_size;
    const float* x   = (const float*)d_in[0];
    const float* Wq  = (const float*)d_in[1];
    const float* Wo  = (const float*)d_in[2];
    const float* bo  = (const float*)d_in[3];
    const float* W1  = (const float*)d_in[4];
    const float* b1  = (const float*)d_in[5];
    const float* W2  = (const float*)d_in[6];
    const float* b2  = (const float*)d_in[7];
    const float* g1  = (const float*)d_in[8];
    const float* be1 = (const float*)d_in[9];
    const float* g2  = (const float*)d_in[10];
    const float* be2 = (const float*)d_in[11];
    float* out = (float*)d_out;

    float* ws = (float*)d_ws;
    const size_t SZ = (size_t)MM * EE;    // 3,145,728 elems / region (12.6 MB fp32)
    float* S1 = ws + SZ;                   // qbf + qbfT (bf16, fills region exactly)
    float* S2 = ws + 2 * SZ;               // catb (bf16)
    float* S3 = ws + 3 * SZ;               // xbf + weight bf16 copies

    unsigned short* qbf  = (unsigned short*)S1;
    unsigned short* qbfT = qbf + (size_t)BB * HH * TT * DD;   // AFTER all of qbf!
    unsigned short* catb = (unsigned short*)S2;
    unsigned short* xbf  = (unsigned short*)S3;
    unsigned short* wqb  = xbf + SZ;
    unsigned short* wob  = wqb + (size_t)EE * EE;
    unsigned short* w1b  = wob + (size_t)EE * EE;
    unsigned short* w2b  = w1b + (size_t)EE * EE;

    k_cvt<<<dim3(3072 + 4 * 144), dim3(256), 0, stream>>>(x, Wq, Wo, W1, W2,
                                                          xbf, wqb, wob, w1b, w2b);
    k_qgemm<<<dim3(MM / 16, 2), dim3(256), 0, stream>>>(xbf, wqb, qbf);
    k_prep<<<dim3(TT / 64, BB * HH), dim3(256), 0, stream>>>(qbf, qbfT);
    k_attn<<<dim3(768), dim3(256), 0, stream>>>(qbf, qbfT, catb);
    k_ffn<<<dim3(MM / 16), dim3(512), 0, stream>>>(catb, wob, bo, x, g1, be1,
                                                   w1b, b1, w2b, b2, g2, be2, out);
}

// Round 17
// 191.821 us; speedup vs baseline: 1.1004x; 1.1004x over previous
//
#include <hip/hip_runtime.h>
#include <math.h>

#define BB 4
#define TT 2048
#define EE 384
#define HH 6
#define DD 64
#define MM (BB*TT)   // 8192 tokens

typedef __attribute__((ext_vector_type(8))) short bf16x8;
typedef __attribute__((ext_vector_type(4))) float f32x4;

__device__ __forceinline__ unsigned short f2bf(float f) {
    unsigned int u = __float_as_uint(f);
    u = (u + 0x7FFFu + ((u >> 16) & 1u)) >> 16;   // RNE
    return (unsigned short)u;
}
__device__ __forceinline__ float bf2f(unsigned short u) {
    return __uint_as_float(((unsigned int)u) << 16);
}
__device__ __forceinline__ unsigned int pk2(float a, float b) {
    return (unsigned int)f2bf(a) | ((unsigned int)f2bf(b) << 16);
}

// ------------- fp32 -> bf16 conversion: x (3072 blocks) + 4 weights (144 each) -------
__global__ __launch_bounds__(256) void k_cvt(const float* __restrict__ x,
                                             const float* __restrict__ wq,
                                             const float* __restrict__ wo,
                                             const float* __restrict__ w1,
                                             const float* __restrict__ w2,
                                             unsigned short* __restrict__ xb,
                                             unsigned short* __restrict__ wqb,
                                             unsigned short* __restrict__ wob,
                                             unsigned short* __restrict__ w1b,
                                             unsigned short* __restrict__ w2b)
{
    int bid = blockIdx.x;
    const float* src; unsigned short* dst; int i;
    if (bid < 3072)       { src = x;  dst = xb;  i = bid * 256; }
    else {
        int r = bid - 3072, wi = r / 144, off = (r % 144) * 256;
        const float* s4[4] = {wq, wo, w1, w2};
        unsigned short* d4[4] = {wqb, wob, w1b, w2b};
        src = s4[wi]; dst = d4[wi]; i = off;
    }
    i += threadIdx.x;
    float4 v = ((const float4*)src)[i];
    uint2 o; o.x = pk2(v.x, v.y); o.y = pk2(v.z, v.w);
    ((uint2*)dst)[i] = o;
}

// ------------- q-GEMM: A bf16, writes qbf[b,h,t,d] bf16 ------------------------------
__global__ __launch_bounds__(256, 4) void k_qgemm(const unsigned short* __restrict__ A,
                                                  const unsigned short* __restrict__ W,
                                                  unsigned short* __restrict__ qbf)
{
    const int tid = threadIdx.x;
    const int w = tid >> 6, lane = tid & 63;
    const int fr = lane & 15, quad = lane >> 4;
    const int m0 = blockIdx.x * 16;
    const int n0 = blockIdx.y * 192 + w * 48;
    const unsigned short* Ap = A + (size_t)(m0 + fr) * EE + quad * 8;
    const unsigned short* Wp = W + (size_t)(n0 + fr) * EE + quad * 8;

    f32x4 acc[3];
    #pragma unroll
    for (int nt = 0; nt < 3; nt++) acc[nt] = (f32x4){0.f, 0.f, 0.f, 0.f};

    #pragma unroll
    for (int k0 = 0; k0 < 12; k0++) {
        bf16x8 a = *(const bf16x8*)(Ap + k0 * 32);
        #pragma unroll
        for (int nt = 0; nt < 3; nt++) {
            bf16x8 b = *(const bf16x8*)(Wp + (size_t)nt * 16 * EE + k0 * 32);
            acc[nt] = __builtin_amdgcn_mfma_f32_16x16x32_bf16(a, b, acc[nt], 0, 0, 0);
        }
    }

    const int mrow = m0 + quad * 4;
    #pragma unroll
    for (int nt = 0; nt < 3; nt++) {
        int n = n0 + nt * 16 + fr;
        int h = n >> 6, d = n & 63;
        #pragma unroll
        for (int r = 0; r < 4; r++) {
            int m = mrow + r;
            int b = m >> 11, t = m & 2047;
            qbf[((size_t)(b * HH + h) * TT + t) * DD + d] = f2bf(acc[nt][r]);
        }
    }
}

// ------------- transpose qbf[b,h,t,d] -> qbfT[b,h,d,t] (bf16, coalesced) -------------
__global__ __launch_bounds__(256) void k_prep(const unsigned short* __restrict__ qbf,
                                              unsigned short* __restrict__ qbfT)
{
    __shared__ unsigned short Ls[64][72];
    const int bh = blockIdx.y;
    const int t0 = blockIdx.x * 64;
    const unsigned short* src = qbf + ((size_t)bh * TT + t0) * DD;
    {
        int r = threadIdx.x >> 2, c = (threadIdx.x & 3) * 16;
        const unsigned short* p = src + (size_t)r * DD + c;
        *(uint4*)&Ls[r][c]     = *(const uint4*)(p);
        *(uint4*)&Ls[r][c + 8] = *(const uint4*)(p + 8);
    }
    __syncthreads();
    {
        int d = threadIdx.x >> 2, tc = (threadIdx.x & 3) * 16;
        unsigned short tmp[16];
        #pragma unroll
        for (int i = 0; i < 16; i++) tmp[i] = Ls[tc + i][d];
        unsigned short* dst = qbfT + ((size_t)bh * DD + d) * TT + t0 + tc;
        *(uint4*)(dst)     = *(const uint4*)&tmp[0];
        *(uint4*)(dst + 8) = *(const uint4*)&tmp[8];
    }
}

// ------------- MFMA flash attention: XCD swizzle + K/V LDS double-buffer -------------
// (unchanged from R16 -- this round measures it cleanly with ffn out of the way)
__global__ __launch_bounds__(256, 4) void k_attn(const unsigned short* __restrict__ qbf,
                                                 const unsigned short* __restrict__ qbfT,
                                                 unsigned short* __restrict__ cat)
{
    __shared__ unsigned short Qs[32][72];
    __shared__ unsigned short Ks[2][64][72];
    __shared__ unsigned short Vs[2][64][72];
    __shared__ unsigned short Ps[32][72];
    __shared__ float lsc[32];
    float (*Oc)[68] = (float(*)[68])&Ks[0][0][0];   // overlay (8704 B <= 9216 B)

    const int id = blockIdx.x;              // 0..767
    const int xcd = id & 7, j = id >> 3;
    const int bh = xcd * 3 + (j % 3);       // XCD-affine: 3 heads per XCD
    const int p = j / 3;                    // 0..31
    const int bb = bh / HH, hh = bh % HH;
    const int tid = threadIdx.x;
    const int w = tid >> 6, lane = tid & 63;
    const int qhalf = w & 1, keyhalf = w >> 1;
    const int fr = lane & 15, quad = lane >> 4;
    const int fc = quad * 8;
    const unsigned short* qb  = qbf  + (size_t)bh * TT * DD;
    const unsigned short* qtb = qbfT + (size_t)bh * DD * TT;
    const int lr = tid >> 2, lc = (tid & 3) * 16;
    const int qr = tid >> 3, qc = (tid & 7) * 8;

    #pragma unroll 1
    for (int ph = 0; ph < 2; ph++) {
        const int tile = ph ? (63 - p) : p;
        const int m0 = tile * 32;
        const int nkt = (tile >> 1) + 1;

        uint4 kr0, kr1, vr0, vr1;
        {
            const unsigned short* kp = qb + (size_t)lr * DD + lc;
            kr0 = *(const uint4*)(kp);
            kr1 = *(const uint4*)(kp + 8);
            const unsigned short* vp = qtb + (size_t)lr * TT + lc;
            vr0 = *(const uint4*)(vp);
            vr1 = *(const uint4*)(vp + 8);
        }

        __syncthreads();   // prev phase fully done (incl. Oc-overlay reads)
        {
            const unsigned short* qp = qb + (size_t)(m0 + qr) * DD + qc;
            *(uint4*)&Qs[qr][qc] = *(const uint4*)(qp);
        }
        *(uint4*)&Ks[0][lr][lc]     = kr0;
        *(uint4*)&Ks[0][lr][lc + 8] = kr1;
        *(uint4*)&Vs[0][lr][lc]     = vr0;
        *(uint4*)&Vs[0][lr][lc + 8] = vr1;
        __syncthreads();   // Qs + buf0 visible
        const bf16x8 qA0 = *(const bf16x8*)&Qs[qhalf * 16 + fr][fc];
        const bf16x8 qA1 = *(const bf16x8*)&Qs[qhalf * 16 + fr][fc + 32];

        f32x4 accO[4];
        #pragma unroll
        for (int dt = 0; dt < 4; dt++) accO[dt] = (f32x4){0.f, 0.f, 0.f, 0.f};
        float ls[4] = {0.f, 0.f, 0.f, 0.f};
        const int rowbase = m0 + qhalf * 16 + quad * 4;
        const int prow = qhalf * 16 + quad * 4;

        for (int kt = 0; kt < nkt; kt++) {
            const int cur = kt & 1;
            const int s0 = kt * 64;
            if (kt < nkt - 1) {
                const unsigned short* kp = qb + (size_t)(s0 + 64 + lr) * DD + lc;
                kr0 = *(const uint4*)(kp);
                kr1 = *(const uint4*)(kp + 8);
                const unsigned short* vp = qtb + (size_t)lr * TT + s0 + 64 + lc;
                vr0 = *(const uint4*)(vp);
                vr1 = *(const uint4*)(vp + 8);
            }

            f32x4 S[2];
            #pragma unroll
            for (int nt = 0; nt < 2; nt++) {
                f32x4 acc = (f32x4){0.f, 0.f, 0.f, 0.f};
                bf16x8 b0 = *(const bf16x8*)&Ks[cur][keyhalf * 32 + nt * 16 + fr][fc];
                acc = __builtin_amdgcn_mfma_f32_16x16x32_bf16(qA0, b0, acc, 0, 0, 0);
                bf16x8 b1 = *(const bf16x8*)&Ks[cur][keyhalf * 32 + nt * 16 + fr][fc + 32];
                acc = __builtin_amdgcn_mfma_f32_16x16x32_bf16(qA1, b1, acc, 0, 0, 0);
                S[nt] = acc;
            }

            #pragma unroll
            for (int nt = 0; nt < 2; nt++) {
                int jg = s0 + keyhalf * 32 + nt * 16 + fr;
                #pragma unroll
                for (int r = 0; r < 4; r++) {
                    float v = S[nt][r] * 0.125f;
                    float pv = (jg <= rowbase + r && v != 0.0f) ? __expf(v) : 0.0f;
                    ls[r] += pv;
                    Ps[prow + r][keyhalf * 32 + nt * 16 + fr] = f2bf(pv);
                }
            }

            bf16x8 pA = *(const bf16x8*)&Ps[qhalf * 16 + fr][keyhalf * 32 + fc];
            #pragma unroll
            for (int dt = 0; dt < 4; dt++) {
                bf16x8 v0 = *(const bf16x8*)&Vs[cur][dt * 16 + fr][keyhalf * 32 + fc];
                accO[dt] = __builtin_amdgcn_mfma_f32_16x16x32_bf16(pA, v0, accO[dt], 0, 0, 0);
            }

            if (kt < nkt - 1) {
                *(uint4*)&Ks[cur ^ 1][lr][lc]     = kr0;
                *(uint4*)&Ks[cur ^ 1][lr][lc + 8] = kr1;
                *(uint4*)&Vs[cur ^ 1][lr][lc]     = vr0;
                *(uint4*)&Vs[cur ^ 1][lr][lc + 8] = vr1;
                __syncthreads();   // single barrier per iteration
            }
        }

        __syncthreads();   // final-iter LDS reads complete before Oc-overlay write
        #pragma unroll
        for (int r = 0; r < 4; r++) {
            #pragma unroll
            for (int o = 1; o < 16; o <<= 1) ls[r] += __shfl_xor(ls[r], o, 64);
        }
        if (keyhalf == 1) {
            #pragma unroll
            for (int dt = 0; dt < 4; dt++)
                #pragma unroll
                for (int r = 0; r < 4; r++)
                    Oc[prow + r][dt * 16 + fr] = accO[dt][r];
            if (fr == 0) {
                #pragma unroll
                for (int r = 0; r < 4; r++) lsc[prow + r] = ls[r];
            }
        }
        __syncthreads();
        if (keyhalf == 0) {
            float lt[4];
            #pragma unroll
            for (int r = 0; r < 4; r++) lt[r] = ls[r] + lsc[prow + r];
            #pragma unroll
            for (int dt = 0; dt < 4; dt++) {
                #pragma unroll
                for (int r = 0; r < 4; r++) {
                    float o = accO[dt][r] + Oc[prow + r][dt * 16 + fr];
                    int t = rowbase + r;
                    cat[((size_t)bb * TT + t) * EE + hh * DD + dt * 16 + fr] =
                        f2bf(o / lt[r]);
                }
            }
        }
    }
}

// ------------- fused proj+LN1 + FFN1 + FFN2+LN2 (R15's proven 32-row version) --------
// 512 threads, 32 rows/block, grid 256. 8 waves each own 32m x 48n (2 m-tiles x 3
// n-tiles): this shape keeps the b-frag double-buffer in registers (the 16-row 1x3
// shape gets sunk to VGPR=36 and regresses to 64 us -- R12, R16).
__global__ __launch_bounds__(512, 2) void k_ffn(const unsigned short* __restrict__ catb,
                                                const unsigned short* __restrict__ wob,
                                                const float* __restrict__ bo,
                                                const float* __restrict__ x,
                                                const float* __restrict__ g1,
                                                const float* __restrict__ be1,
                                                const unsigned short* __restrict__ w1b,
                                                const float* __restrict__ b1,
                                                const unsigned short* __restrict__ w2b,
                                                const float* __restrict__ b2,
                                                const float* __restrict__ g2,
                                                const float* __restrict__ be2,
                                                float* __restrict__ out)
{
    __shared__ unsigned short X1s[32][392];
    __shared__ unsigned short H1s[32][392];
    __shared__ float ssum[32][8];
    __shared__ float ssq[32][8];
    const int tid = threadIdx.x;
    const int w = tid >> 6, lane = tid & 63;
    const int fr = lane & 15, quad = lane >> 4;
    const int m0 = blockIdx.x * 32;
    const int n0 = w * 48;

    f32x4 acc[2][3];
    bf16x8 bc[3], bn[3];

    // ================= GEMM1: proj = catb @ Wo^T (2 m-tiles) =================
    {
        const unsigned short* Ap0 = catb + (size_t)(m0 + fr) * EE + quad * 8;
        const unsigned short* Ap1 = Ap0 + 16 * EE;
        const unsigned short* Wp = wob + (size_t)(n0 + fr) * EE + quad * 8;
        #pragma unroll
        for (int mt = 0; mt < 2; mt++)
            #pragma unroll
            for (int nt = 0; nt < 3; nt++) acc[mt][nt] = (f32x4){0.f, 0.f, 0.f, 0.f};
        #pragma unroll
        for (int nt = 0; nt < 3; nt++) bc[nt] = *(const bf16x8*)(Wp + (size_t)nt * 16 * EE);
        #pragma unroll
        for (int k0 = 0; k0 < 12; k0++) {
            if (k0 < 11) {
                #pragma unroll
                for (int nt = 0; nt < 3; nt++)
                    bn[nt] = *(const bf16x8*)(Wp + (size_t)nt * 16 * EE + (k0 + 1) * 32);
            }
            bf16x8 a0 = *(const bf16x8*)(Ap0 + k0 * 32);
            bf16x8 a1 = *(const bf16x8*)(Ap1 + k0 * 32);
            #pragma unroll
            for (int nt = 0; nt < 3; nt++) {
                acc[0][nt] = __builtin_amdgcn_mfma_f32_16x16x32_bf16(a0, bc[nt], acc[0][nt], 0, 0, 0);
                acc[1][nt] = __builtin_amdgcn_mfma_f32_16x16x32_bf16(a1, bc[nt], acc[1][nt], 0, 0, 0);
            }
            #pragma unroll
            for (int nt = 0; nt < 3; nt++) bc[nt] = bn[nt];
        }
    }
    // + bo + resid(x) -> LN1 stats
    {
        float s1[2][4] = {{0.f,0.f,0.f,0.f},{0.f,0.f,0.f,0.f}};
        float s2[2][4] = {{0.f,0.f,0.f,0.f},{0.f,0.f,0.f,0.f}};
        #pragma unroll
        for (int nt = 0; nt < 3; nt++) {
            int n = n0 + nt * 16 + fr;
            float bv = bo[n];
            #pragma unroll
            for (int mt = 0; mt < 2; mt++)
                #pragma unroll
                for (int r = 0; r < 4; r++) {
                    float v = acc[mt][nt][r] + bv
                            + x[(size_t)(m0 + mt * 16 + quad * 4 + r) * EE + n];
                    acc[mt][nt][r] = v;
                    s1[mt][r] += v;
                    s2[mt][r] += v * v;
                }
        }
        #pragma unroll
        for (int mt = 0; mt < 2; mt++)
            #pragma unroll
            for (int r = 0; r < 4; r++) {
                #pragma unroll
                for (int o = 1; o < 16; o <<= 1) {
                    s1[mt][r] += __shfl_xor(s1[mt][r], o, 64);
                    s2[mt][r] += __shfl_xor(s2[mt][r], o, 64);
                }
            }
        if (fr == 0) {
            #pragma unroll
            for (int mt = 0; mt < 2; mt++)
                #pragma unroll
                for (int r = 0; r < 4; r++) {
                    ssum[mt * 16 + quad * 4 + r][w] = s1[mt][r];
                    ssq [mt * 16 + quad * 4 + r][w] = s2[mt][r];
                }
        }
    }
    __syncthreads();
    {
        #pragma unroll
        for (int mt = 0; mt < 2; mt++) {
            float mu[4], rs[4];
            #pragma unroll
            for (int r = 0; r < 4; r++) {
                int row = mt * 16 + quad * 4 + r;
                float t1 = 0.f, t2 = 0.f;
                #pragma unroll
                for (int q = 0; q < 8; q++) { t1 += ssum[row][q]; t2 += ssq[row][q]; }
                mu[r] = t1 * (1.0f / EE);
                float var = t2 * (1.0f / EE) - mu[r] * mu[r];
                rs[r] = rsqrtf(var + 1e-5f);
            }
            #pragma unroll
            for (int nt = 0; nt < 3; nt++) {
                int n = n0 + nt * 16 + fr;
                float gv = g1[n], bev = be1[n];
                #pragma unroll
                for (int r = 0; r < 4; r++) {
                    float v = (acc[mt][nt][r] - mu[r]) * rs[r] * gv + bev;
                    X1s[mt * 16 + quad * 4 + r][n] = f2bf(v);
                }
            }
        }
    }
    __syncthreads();

    // ================= GEMM2: h1 = relu(x1 @ W1^T + b1) =================
    {
        const unsigned short* Wp = w1b + (size_t)(n0 + fr) * EE + quad * 8;
        #pragma unroll
        for (int mt = 0; mt < 2; mt++)
            #pragma unroll
            for (int nt = 0; nt < 3; nt++) acc[mt][nt] = (f32x4){0.f, 0.f, 0.f, 0.f};
        #pragma unroll
        for (int nt = 0; nt < 3; nt++) bc[nt] = *(const bf16x8*)(Wp + (size_t)nt * 16 * EE);
        #pragma unroll
        for (int k0 = 0; k0 < 12; k0++) {
            if (k0 < 11) {
                #pragma unroll
                for (int nt = 0; nt < 3; nt++)
                    bn[nt] = *(const bf16x8*)(Wp + (size_t)nt * 16 * EE + (k0 + 1) * 32);
            }
            bf16x8 a0 = *(const bf16x8*)&X1s[fr][k0 * 32 + quad * 8];
            bf16x8 a1 = *(const bf16x8*)&X1s[16 + fr][k0 * 32 + quad * 8];
            #pragma unroll
            for (int nt = 0; nt < 3; nt++) {
                acc[0][nt] = __builtin_amdgcn_mfma_f32_16x16x32_bf16(a0, bc[nt], acc[0][nt], 0, 0, 0);
                acc[1][nt] = __builtin_amdgcn_mfma_f32_16x16x32_bf16(a1, bc[nt], acc[1][nt], 0, 0, 0);
            }
            #pragma unroll
            for (int nt = 0; nt < 3; nt++) bc[nt] = bn[nt];
        }
        #pragma unroll
        for (int nt = 0; nt < 3; nt++) {
            int n = n0 + nt * 16 + fr;
            float bv = b1[n];
            #pragma unroll
            for (int mt = 0; mt < 2; mt++)
                #pragma unroll
                for (int r = 0; r < 4; r++)
                    H1s[mt * 16 + quad * 4 + r][n] = f2bf(fmaxf(acc[mt][nt][r] + bv, 0.0f));
        }
    }
    __syncthreads();

    // ================= GEMM3: ff = h1 @ W2^T + b2; LN2(x1 + ff) -> out =================
    {
        const unsigned short* Wp = w2b + (size_t)(n0 + fr) * EE + quad * 8;
        #pragma unroll
        for (int mt = 0; mt < 2; mt++)
            #pragma unroll
            for (int nt = 0; nt < 3; nt++) acc[mt][nt] = (f32x4){0.f, 0.f, 0.f, 0.f};
        #pragma unroll
        for (int nt = 0; nt < 3; nt++) bc[nt] = *(const bf16x8*)(Wp + (size_t)nt * 16 * EE);
        #pragma unroll
        for (int k0 = 0; k0 < 12; k0++) {
            if (k0 < 11) {
                #pragma unroll
                for (int nt = 0; nt < 3; nt++)
                    bn[nt] = *(const bf16x8*)(Wp + (size_t)nt * 16 * EE + (k0 + 1) * 32);
            }
            bf16x8 a0 = *(const bf16x8*)&H1s[fr][k0 * 32 + quad * 8];
            bf16x8 a1 = *(const bf16x8*)&H1s[16 + fr][k0 * 32 + quad * 8];
            #pragma unroll
            for (int nt = 0; nt < 3; nt++) {
                acc[0][nt] = __builtin_amdgcn_mfma_f32_16x16x32_bf16(a0, bc[nt], acc[0][nt], 0, 0, 0);
                acc[1][nt] = __builtin_amdgcn_mfma_f32_16x16x32_bf16(a1, bc[nt], acc[1][nt], 0, 0, 0);
            }
            #pragma unroll
            for (int nt = 0; nt < 3; nt++) bc[nt] = bn[nt];
        }
    }
    {
        float s1[2][4] = {{0.f,0.f,0.f,0.f},{0.f,0.f,0.f,0.f}};
        float s2[2][4] = {{0.f,0.f,0.f,0.f},{0.f,0.f,0.f,0.f}};
        #pragma unroll
        for (int nt = 0; nt < 3; nt++) {
            int n = n0 + nt * 16 + fr;
            float bv = b2[n];
            #pragma unroll
            for (int mt = 0; mt < 2; mt++)
                #pragma unroll
                for (int r = 0; r < 4; r++) {
                    float v = acc[mt][nt][r] + bv + bf2f(X1s[mt * 16 + quad * 4 + r][n]);
                    acc[mt][nt][r] = v;
                    s1[mt][r] += v;
                    s2[mt][r] += v * v;
                }
        }
        #pragma unroll
        for (int mt = 0; mt < 2; mt++)
            #pragma unroll
            for (int r = 0; r < 4; r++) {
                #pragma unroll
                for (int o = 1; o < 16; o <<= 1) {
                    s1[mt][r] += __shfl_xor(s1[mt][r], o, 64);
                    s2[mt][r] += __shfl_xor(s2[mt][r], o, 64);
                }
            }
        if (fr == 0) {
            #pragma unroll
            for (int mt = 0; mt < 2; mt++)
                #pragma unroll
                for (int r = 0; r < 4; r++) {
                    ssum[mt * 16 + quad * 4 + r][w] = s1[mt][r];
                    ssq [mt * 16 + quad * 4 + r][w] = s2[mt][r];
                }
        }
    }
    __syncthreads();
    {
        #pragma unroll
        for (int mt = 0; mt < 2; mt++) {
            float mu[4], rs[4];
            #pragma unroll
            for (int r = 0; r < 4; r++) {
                int row = mt * 16 + quad * 4 + r;
                float u1 = 0.f, u2 = 0.f;
                #pragma unroll
                for (int q = 0; q < 8; q++) { u1 += ssum[row][q]; u2 += ssq[row][q]; }
                mu[r] = u1 * (1.0f / EE);
                float var = u2 * (1.0f / EE) - mu[r] * mu[r];
                rs[r] = rsqrtf(var + 1e-5f);
            }
            #pragma unroll
            for (int nt = 0; nt < 3; nt++) {
                int n = n0 + nt * 16 + fr;
                float gv = g2[n], bev = be2[n];
                #pragma unroll
                for (int r = 0; r < 4; r++)
                    out[(size_t)(m0 + mt * 16 + quad * 4 + r) * EE + n] =
                        (acc[mt][nt][r] - mu[r]) * rs[r] * gv + bev;
            }
        }
    }
}

extern "C" void kernel_launch(void* const* d_in, const int* in_sizes, int n_in,
                              void* d_out, int out_size, void* d_ws, size_t ws_size,
                              hipStream_t stream) {
    (void)in_sizes; (void)n_in; (void)out_size; (void)ws_size;
    const float* x   = (const float*)d_in[0];
    const float* Wq  = (const float*)d_in[1];
    const float* Wo  = (const float*)d_in[2];
    const float* bo  = (const float*)d_in[3];
    const float* W1  = (const float*)d_in[4];
    const float* b1  = (const float*)d_in[5];
    const float* W2  = (const float*)d_in[6];
    const float* b2  = (const float*)d_in[7];
    const float* g1  = (const float*)d_in[8];
    const float* be1 = (const float*)d_in[9];
    const float* g2  = (const float*)d_in[10];
    const float* be2 = (const float*)d_in[11];
    float* out = (float*)d_out;

    float* ws = (float*)d_ws;
    const size_t SZ = (size_t)MM * EE;    // 3,145,728 elems / region (12.6 MB fp32)
    float* S1 = ws + SZ;                   // qbf + qbfT (bf16, fills region exactly)
    float* S2 = ws + 2 * SZ;               // catb (bf16)
    float* S3 = ws + 3 * SZ;               // xbf + weight bf16 copies

    unsigned short* qbf  = (unsigned short*)S1;
    unsigned short* qbfT = qbf + (size_t)BB * HH * TT * DD;   // AFTER all of qbf!
    unsigned short* catb = (unsigned short*)S2;
    unsigned short* xbf  = (unsigned short*)S3;
    unsigned short* wqb  = xbf + SZ;
    unsigned short* wob  = wqb + (size_t)EE * EE;
    unsigned short* w1b  = wob + (size_t)EE * EE;
    unsigned short* w2b  = w1b + (size_t)EE * EE;

    k_cvt<<<dim3(3072 + 4 * 144), dim3(256), 0, stream>>>(x, Wq, Wo, W1, W2,
                                                          xbf, wqb, wob, w1b, w2b);
    k_qgemm<<<dim3(MM / 16, 2), dim3(256), 0, stream>>>(xbf, wqb, qbf);
    k_prep<<<dim3(TT / 64, BB * HH), dim3(256), 0, stream>>>(qbf, qbfT);
    k_attn<<<dim3(768), dim3(256), 0, stream>>>(qbf, qbfT, catb);
    k_ffn<<<dim3(MM / 32), dim3(512), 0, stream>>>(catb, wob, bo, x, g1, be1,
                                                   w1b, b1, w2b, b2, g2, be2, out);
}

// Round 18
// 182.354 us; speedup vs baseline: 1.1576x; 1.0519x over previous
//
#include <hip/hip_runtime.h>
#include <math.h>

#define BB 4
#define TT 2048
#define EE 384
#define HH 6
#define DD 64
#define MM (BB*TT)   // 8192 tokens

typedef __attribute__((ext_vector_type(8))) short bf16x8;
typedef __attribute__((ext_vector_type(4))) float f32x4;

__device__ __forceinline__ unsigned short f2bf(float f) {
    unsigned int u = __float_as_uint(f);
    u = (u + 0x7FFFu + ((u >> 16) & 1u)) >> 16;   // RNE
    return (unsigned short)u;
}
__device__ __forceinline__ float bf2f(unsigned short u) {
    return __uint_as_float(((unsigned int)u) << 16);
}
__device__ __forceinline__ unsigned int pk2(float a, float b) {
    return (unsigned int)f2bf(a) | ((unsigned int)f2bf(b) << 16);
}

// ------------- fp32 -> bf16 conversion: x (3072 blocks) + 4 weights (144 each) -------
__global__ __launch_bounds__(256) void k_cvt(const float* __restrict__ x,
                                             const float* __restrict__ wq,
                                             const float* __restrict__ wo,
                                             const float* __restrict__ w1,
                                             const float* __restrict__ w2,
                                             unsigned short* __restrict__ xb,
                                             unsigned short* __restrict__ wqb,
                                             unsigned short* __restrict__ wob,
                                             unsigned short* __restrict__ w1b,
                                             unsigned short* __restrict__ w2b)
{
    int bid = blockIdx.x;
    const float* src; unsigned short* dst; int i;
    if (bid < 3072)       { src = x;  dst = xb;  i = bid * 256; }
    else {
        int r = bid - 3072, wi = r / 144, off = (r % 144) * 256;
        const float* s4[4] = {wq, wo, w1, w2};
        unsigned short* d4[4] = {wqb, wob, w1b, w2b};
        src = s4[wi]; dst = d4[wi]; i = off;
    }
    i += threadIdx.x;
    float4 v = ((const float4*)src)[i];
    uint2 o; o.x = pk2(v.x, v.y); o.y = pk2(v.z, v.w);
    ((uint2*)dst)[i] = o;
}

// ------------- q-GEMM: 32 rows/block, b-frag double-buffer, fused qbfT epilogue ------
// Wave shape 32m x 48n (2 m-tiles x 3 n-tiles) -- the shape proven (R11/R15 ffn) to
// keep the weight prefetch in registers. Epilogue stages the 32x192 tile in LDS and
// writes qbfT[b,h,d,t] coalesced (64B/column), replacing the separate k_prep pass.
__global__ __launch_bounds__(256, 2) void k_qgemm(const unsigned short* __restrict__ A,
                                                  const unsigned short* __restrict__ W,
                                                  unsigned short* __restrict__ qbf,
                                                  unsigned short* __restrict__ qbfT)
{
    __shared__ unsigned short Ts[32][200];
    const int tid = threadIdx.x;
    const int w = tid >> 6, lane = tid & 63;
    const int fr = lane & 15, quad = lane >> 4;
    const int m0 = blockIdx.x * 32;
    const int n0 = blockIdx.y * 192 + w * 48;
    const unsigned short* Ap0 = A + (size_t)(m0 + fr) * EE + quad * 8;
    const unsigned short* Ap1 = Ap0 + 16 * EE;
    const unsigned short* Wp = W + (size_t)(n0 + fr) * EE + quad * 8;

    f32x4 acc[2][3];
    bf16x8 bc[3], bn[3];
    #pragma unroll
    for (int mt = 0; mt < 2; mt++)
        #pragma unroll
        for (int nt = 0; nt < 3; nt++) acc[mt][nt] = (f32x4){0.f, 0.f, 0.f, 0.f};
    #pragma unroll
    for (int nt = 0; nt < 3; nt++) bc[nt] = *(const bf16x8*)(Wp + (size_t)nt * 16 * EE);

    #pragma unroll
    for (int k0 = 0; k0 < 12; k0++) {
        if (k0 < 11) {
            #pragma unroll
            for (int nt = 0; nt < 3; nt++)
                bn[nt] = *(const bf16x8*)(Wp + (size_t)nt * 16 * EE + (k0 + 1) * 32);
        }
        bf16x8 a0 = *(const bf16x8*)(Ap0 + k0 * 32);
        bf16x8 a1 = *(const bf16x8*)(Ap1 + k0 * 32);
        #pragma unroll
        for (int nt = 0; nt < 3; nt++) {
            acc[0][nt] = __builtin_amdgcn_mfma_f32_16x16x32_bf16(a0, bc[nt], acc[0][nt], 0, 0, 0);
            acc[1][nt] = __builtin_amdgcn_mfma_f32_16x16x32_bf16(a1, bc[nt], acc[1][nt], 0, 0, 0);
        }
        #pragma unroll
        for (int nt = 0; nt < 3; nt++) bc[nt] = bn[nt];
    }

    // epilogue: direct qbf writes + LDS stage for transposed qbfT
    const int bglob = m0 >> 11, t0 = m0 & 2047;
    #pragma unroll
    for (int nt = 0; nt < 3; nt++) {
        int nl = w * 48 + nt * 16 + fr;
        int n = blockIdx.y * 192 + nl;
        int h = n >> 6, d = n & 63;
        #pragma unroll
        for (int mt = 0; mt < 2; mt++)
            #pragma unroll
            for (int r = 0; r < 4; r++) {
                int ml = mt * 16 + quad * 4 + r;
                unsigned short bf = f2bf(acc[mt][nt][r]);
                qbf[((size_t)(bglob * HH + h) * TT + t0 + ml) * DD + d] = bf;
                Ts[ml][nl] = bf;
            }
    }
    __syncthreads();
    if (tid < 192) {
        int nl = tid;
        int n = blockIdx.y * 192 + nl;
        int h = n >> 6, d = n & 63;
        unsigned short tmp[32];
        #pragma unroll
        for (int i = 0; i < 32; i++) tmp[i] = Ts[i][nl];
        unsigned short* dst = qbfT + ((size_t)(bglob * HH + h) * DD + d) * TT + t0;
        *(uint4*)(dst)      = *(const uint4*)&tmp[0];
        *(uint4*)(dst + 8)  = *(const uint4*)&tmp[8];
        *(uint4*)(dst + 16) = *(const uint4*)&tmp[16];
        *(uint4*)(dst + 24) = *(const uint4*)&tmp[24];
    }
}

// ------------- MFMA flash attention: XCD swizzle + K/V LDS double-buffer (R17) -------
__global__ __launch_bounds__(256, 4) void k_attn(const unsigned short* __restrict__ qbf,
                                                 const unsigned short* __restrict__ qbfT,
                                                 unsigned short* __restrict__ cat)
{
    __shared__ unsigned short Qs[32][72];
    __shared__ unsigned short Ks[2][64][72];
    __shared__ unsigned short Vs[2][64][72];
    __shared__ unsigned short Ps[32][72];
    __shared__ float lsc[32];
    float (*Oc)[68] = (float(*)[68])&Ks[0][0][0];   // overlay (8704 B <= 9216 B)

    const int id = blockIdx.x;              // 0..767
    const int xcd = id & 7, j = id >> 3;
    const int bh = xcd * 3 + (j % 3);       // XCD-affine: 3 heads per XCD
    const int p = j / 3;                    // 0..31
    const int bb = bh / HH, hh = bh % HH;
    const int tid = threadIdx.x;
    const int w = tid >> 6, lane = tid & 63;
    const int qhalf = w & 1, keyhalf = w >> 1;
    const int fr = lane & 15, quad = lane >> 4;
    const int fc = quad * 8;
    const unsigned short* qb  = qbf  + (size_t)bh * TT * DD;
    const unsigned short* qtb = qbfT + (size_t)bh * DD * TT;
    const int lr = tid >> 2, lc = (tid & 3) * 16;
    const int qr = tid >> 3, qc = (tid & 7) * 8;

    #pragma unroll 1
    for (int ph = 0; ph < 2; ph++) {
        const int tile = ph ? (63 - p) : p;
        const int m0 = tile * 32;
        const int nkt = (tile >> 1) + 1;

        uint4 kr0, kr1, vr0, vr1;
        {
            const unsigned short* kp = qb + (size_t)lr * DD + lc;
            kr0 = *(const uint4*)(kp);
            kr1 = *(const uint4*)(kp + 8);
            const unsigned short* vp = qtb + (size_t)lr * TT + lc;
            vr0 = *(const uint4*)(vp);
            vr1 = *(const uint4*)(vp + 8);
        }

        __syncthreads();   // prev phase fully done (incl. Oc-overlay reads)
        {
            const unsigned short* qp = qb + (size_t)(m0 + qr) * DD + qc;
            *(uint4*)&Qs[qr][qc] = *(const uint4*)(qp);
        }
        *(uint4*)&Ks[0][lr][lc]     = kr0;
        *(uint4*)&Ks[0][lr][lc + 8] = kr1;
        *(uint4*)&Vs[0][lr][lc]     = vr0;
        *(uint4*)&Vs[0][lr][lc + 8] = vr1;
        __syncthreads();   // Qs + buf0 visible
        const bf16x8 qA0 = *(const bf16x8*)&Qs[qhalf * 16 + fr][fc];
        const bf16x8 qA1 = *(const bf16x8*)&Qs[qhalf * 16 + fr][fc + 32];

        f32x4 accO[4];
        #pragma unroll
        for (int dt = 0; dt < 4; dt++) accO[dt] = (f32x4){0.f, 0.f, 0.f, 0.f};
        float ls[4] = {0.f, 0.f, 0.f, 0.f};
        const int rowbase = m0 + qhalf * 16 + quad * 4;
        const int prow = qhalf * 16 + quad * 4;

        for (int kt = 0; kt < nkt; kt++) {
            const int cur = kt & 1;
            const int s0 = kt * 64;
            if (kt < nkt - 1) {
                const unsigned short* kp = qb + (size_t)(s0 + 64 + lr) * DD + lc;
                kr0 = *(const uint4*)(kp);
                kr1 = *(const uint4*)(kp + 8);
                const unsigned short* vp = qtb + (size_t)lr * TT + s0 + 64 + lc;
                vr0 = *(const uint4*)(vp);
                vr1 = *(const uint4*)(vp + 8);
            }

            f32x4 S[2];
            #pragma unroll
            for (int nt = 0; nt < 2; nt++) {
                f32x4 acc = (f32x4){0.f, 0.f, 0.f, 0.f};
                bf16x8 b0 = *(const bf16x8*)&Ks[cur][keyhalf * 32 + nt * 16 + fr][fc];
                acc = __builtin_amdgcn_mfma_f32_16x16x32_bf16(qA0, b0, acc, 0, 0, 0);
                bf16x8 b1 = *(const bf16x8*)&Ks[cur][keyhalf * 32 + nt * 16 + fr][fc + 32];
                acc = __builtin_amdgcn_mfma_f32_16x16x32_bf16(qA1, b1, acc, 0, 0, 0);
                S[nt] = acc;
            }

            #pragma unroll
            for (int nt = 0; nt < 2; nt++) {
                int jg = s0 + keyhalf * 32 + nt * 16 + fr;
                #pragma unroll
                for (int r = 0; r < 4; r++) {
                    float v = S[nt][r] * 0.125f;
                    float pv = (jg <= rowbase + r && v != 0.0f) ? __expf(v) : 0.0f;
                    ls[r] += pv;
                    Ps[prow + r][keyhalf * 32 + nt * 16 + fr] = f2bf(pv);
                }
            }

            bf16x8 pA = *(const bf16x8*)&Ps[qhalf * 16 + fr][keyhalf * 32 + fc];
            #pragma unroll
            for (int dt = 0; dt < 4; dt++) {
                bf16x8 v0 = *(const bf16x8*)&Vs[cur][dt * 16 + fr][keyhalf * 32 + fc];
                accO[dt] = __builtin_amdgcn_mfma_f32_16x16x32_bf16(pA, v0, accO[dt], 0, 0, 0);
            }

            if (kt < nkt - 1) {
                *(uint4*)&Ks[cur ^ 1][lr][lc]     = kr0;
                *(uint4*)&Ks[cur ^ 1][lr][lc + 8] = kr1;
                *(uint4*)&Vs[cur ^ 1][lr][lc]     = vr0;
                *(uint4*)&Vs[cur ^ 1][lr][lc + 8] = vr1;
                __syncthreads();   // single barrier per iteration
            }
        }

        __syncthreads();   // final-iter LDS reads complete before Oc-overlay write
        #pragma unroll
        for (int r = 0; r < 4; r++) {
            #pragma unroll
            for (int o = 1; o < 16; o <<= 1) ls[r] += __shfl_xor(ls[r], o, 64);
        }
        if (keyhalf == 1) {
            #pragma unroll
            for (int dt = 0; dt < 4; dt++)
                #pragma unroll
                for (int r = 0; r < 4; r++)
                    Oc[prow + r][dt * 16 + fr] = accO[dt][r];
            if (fr == 0) {
                #pragma unroll
                for (int r = 0; r < 4; r++) lsc[prow + r] = ls[r];
            }
        }
        __syncthreads();
        if (keyhalf == 0) {
            float lt[4];
            #pragma unroll
            for (int r = 0; r < 4; r++) lt[r] = ls[r] + lsc[prow + r];
            #pragma unroll
            for (int dt = 0; dt < 4; dt++) {
                #pragma unroll
                for (int r = 0; r < 4; r++) {
                    float o = accO[dt][r] + Oc[prow + r][dt * 16 + fr];
                    int t = rowbase + r;
                    cat[((size_t)bb * TT + t) * EE + hh * DD + dt * 16 + fr] =
                        f2bf(o / lt[r]);
                }
            }
        }
    }
}

// ------------- fused proj+LN1 + FFN1 + FFN2+LN2 (R15/R17 proven 32-row version) ------
__global__ __launch_bounds__(512, 2) void k_ffn(const unsigned short* __restrict__ catb,
                                                const unsigned short* __restrict__ wob,
                                                const float* __restrict__ bo,
                                                const float* __restrict__ x,
                                                const float* __restrict__ g1,
                                                const float* __restrict__ be1,
                                                const unsigned short* __restrict__ w1b,
                                                const float* __restrict__ b1,
                                                const unsigned short* __restrict__ w2b,
                                                const float* __restrict__ b2,
                                                const float* __restrict__ g2,
                                                const float* __restrict__ be2,
                                                float* __restrict__ out)
{
    __shared__ unsigned short X1s[32][392];
    __shared__ unsigned short H1s[32][392];
    __shared__ float ssum[32][8];
    __shared__ float ssq[32][8];
    const int tid = threadIdx.x;
    const int w = tid >> 6, lane = tid & 63;
    const int fr = lane & 15, quad = lane >> 4;
    const int m0 = blockIdx.x * 32;
    const int n0 = w * 48;

    f32x4 acc[2][3];
    bf16x8 bc[3], bn[3];

    // ================= GEMM1: proj = catb @ Wo^T (2 m-tiles) =================
    {
        const unsigned short* Ap0 = catb + (size_t)(m0 + fr) * EE + quad * 8;
        const unsigned short* Ap1 = Ap0 + 16 * EE;
        const unsigned short* Wp = wob + (size_t)(n0 + fr) * EE + quad * 8;
        #pragma unroll
        for (int mt = 0; mt < 2; mt++)
            #pragma unroll
            for (int nt = 0; nt < 3; nt++) acc[mt][nt] = (f32x4){0.f, 0.f, 0.f, 0.f};
        #pragma unroll
        for (int nt = 0; nt < 3; nt++) bc[nt] = *(const bf16x8*)(Wp + (size_t)nt * 16 * EE);
        #pragma unroll
        for (int k0 = 0; k0 < 12; k0++) {
            if (k0 < 11) {
                #pragma unroll
                for (int nt = 0; nt < 3; nt++)
                    bn[nt] = *(const bf16x8*)(Wp + (size_t)nt * 16 * EE + (k0 + 1) * 32);
            }
            bf16x8 a0 = *(const bf16x8*)(Ap0 + k0 * 32);
            bf16x8 a1 = *(const bf16x8*)(Ap1 + k0 * 32);
            #pragma unroll
            for (int nt = 0; nt < 3; nt++) {
                acc[0][nt] = __builtin_amdgcn_mfma_f32_16x16x32_bf16(a0, bc[nt], acc[0][nt], 0, 0, 0);
                acc[1][nt] = __builtin_amdgcn_mfma_f32_16x16x32_bf16(a1, bc[nt], acc[1][nt], 0, 0, 0);
            }
            #pragma unroll
            for (int nt = 0; nt < 3; nt++) bc[nt] = bn[nt];
        }
    }
    // + bo + resid(x) -> LN1 stats
    {
        float s1[2][4] = {{0.f,0.f,0.f,0.f},{0.f,0.f,0.f,0.f}};
        float s2[2][4] = {{0.f,0.f,0.f,0.f},{0.f,0.f,0.f,0.f}};
        #pragma unroll
        for (int nt = 0; nt < 3; nt++) {
            int n = n0 + nt * 16 + fr;
            float bv = bo[n];
            #pragma unroll
            for (int mt = 0; mt < 2; mt++)
                #pragma unroll
                for (int r = 0; r < 4; r++) {
                    float v = acc[mt][nt][r] + bv
                            + x[(size_t)(m0 + mt * 16 + quad * 4 + r) * EE + n];
                    acc[mt][nt][r] = v;
                    s1[mt][r] += v;
                    s2[mt][r] += v * v;
                }
        }
        #pragma unroll
        for (int mt = 0; mt < 2; mt++)
            #pragma unroll
            for (int r = 0; r < 4; r++) {
                #pragma unroll
                for (int o = 1; o < 16; o <<= 1) {
                    s1[mt][r] += __shfl_xor(s1[mt][r], o, 64);
                    s2[mt][r] += __shfl_xor(s2[mt][r], o, 64);
                }
            }
        if (fr == 0) {
            #pragma unroll
            for (int mt = 0; mt < 2; mt++)
                #pragma unroll
                for (int r = 0; r < 4; r++) {
                    ssum[mt * 16 + quad * 4 + r][w] = s1[mt][r];
                    ssq [mt * 16 + quad * 4 + r][w] = s2[mt][r];
                }
        }
    }
    __syncthreads();
    {
        #pragma unroll
        for (int mt = 0; mt < 2; mt++) {
            float mu[4], rs[4];
            #pragma unroll
            for (int r = 0; r < 4; r++) {
                int row = mt * 16 + quad * 4 + r;
                float t1 = 0.f, t2 = 0.f;
                #pragma unroll
                for (int q = 0; q < 8; q++) { t1 += ssum[row][q]; t2 += ssq[row][q]; }
                mu[r] = t1 * (1.0f / EE);
                float var = t2 * (1.0f / EE) - mu[r] * mu[r];
                rs[r] = rsqrtf(var + 1e-5f);
            }
            #pragma unroll
            for (int nt = 0; nt < 3; nt++) {
                int n = n0 + nt * 16 + fr;
                float gv = g1[n], bev = be1[n];
                #pragma unroll
                for (int r = 0; r < 4; r++) {
                    float v = (acc[mt][nt][r] - mu[r]) * rs[r] * gv + bev;
                    X1s[mt * 16 + quad * 4 + r][n] = f2bf(v);
                }
            }
        }
    }
    __syncthreads();

    // ================= GEMM2: h1 = relu(x1 @ W1^T + b1) =================
    {
        const unsigned short* Wp = w1b + (size_t)(n0 + fr) * EE + quad * 8;
        #pragma unroll
        for (int mt = 0; mt < 2; mt++)
            #pragma unroll
            for (int nt = 0; nt < 3; nt++) acc[mt][nt] = (f32x4){0.f, 0.f, 0.f, 0.f};
        #pragma unroll
        for (int nt = 0; nt < 3; nt++) bc[nt] = *(const bf16x8*)(Wp + (size_t)nt * 16 * EE);
        #pragma unroll
        for (int k0 = 0; k0 < 12; k0++) {
            if (k0 < 11) {
                #pragma unroll
                for (int nt = 0; nt < 3; nt++)
                    bn[nt] = *(const bf16x8*)(Wp + (size_t)nt * 16 * EE + (k0 + 1) * 32);
            }
            bf16x8 a0 = *(const bf16x8*)&X1s[fr][k0 * 32 + quad * 8];
            bf16x8 a1 = *(const bf16x8*)&X1s[16 + fr][k0 * 32 + quad * 8];
            #pragma unroll
            for (int nt = 0; nt < 3; nt++) {
                acc[0][nt] = __builtin_amdgcn_mfma_f32_16x16x32_bf16(a0, bc[nt], acc[0][nt], 0, 0, 0);
                acc[1][nt] = __builtin_amdgcn_mfma_f32_16x16x32_bf16(a1, bc[nt], acc[1][nt], 0, 0, 0);
            }
            #pragma unroll
            for (int nt = 0; nt < 3; nt++) bc[nt] = bn[nt];
        }
        #pragma unroll
        for (int nt = 0; nt < 3; nt++) {
            int n = n0 + nt * 16 + fr;
            float bv = b1[n];
            #pragma unroll
            for (int mt = 0; mt < 2; mt++)
                #pragma unroll
                for (int r = 0; r < 4; r++)
                    H1s[mt * 16 + quad * 4 + r][n] = f2bf(fmaxf(acc[mt][nt][r] + bv, 0.0f));
        }
    }
    __syncthreads();

    // ================= GEMM3: ff = h1 @ W2^T + b2; LN2(x1 + ff) -> out =================
    {
        const unsigned short* Wp = w2b + (size_t)(n0 + fr) * EE + quad * 8;
        #pragma unroll
        for (int mt = 0; mt < 2; mt++)
            #pragma unroll
            for (int nt = 0; nt < 3; nt++) acc[mt][nt] = (f32x4){0.f, 0.f, 0.f, 0.f};
        #pragma unroll
        for (int nt = 0; nt < 3; nt++) bc[nt] = *(const bf16x8*)(Wp + (size_t)nt * 16 * EE);
        #pragma unroll
        for (int k0 = 0; k0 < 12; k0++) {
            if (k0 < 11) {
                #pragma unroll
                for (int nt = 0; nt < 3; nt++)
                    bn[nt] = *(const bf16x8*)(Wp + (size_t)nt * 16 * EE + (k0 + 1) * 32);
            }
            bf16x8 a0 = *(const bf16x8*)&H1s[fr][k0 * 32 + quad * 8];
            bf16x8 a1 = *(const bf16x8*)&H1s[16 + fr][k0 * 32 + quad * 8];
            #pragma unroll
            for (int nt = 0; nt < 3; nt++) {
                acc[0][nt] = __builtin_amdgcn_mfma_f32_16x16x32_bf16(a0, bc[nt], acc[0][nt], 0, 0, 0);
                acc[1][nt] = __builtin_amdgcn_mfma_f32_16x16x32_bf16(a1, bc[nt], acc[1][nt], 0, 0, 0);
            }
            #pragma unroll
            for (int nt = 0; nt < 3; nt++) bc[nt] = bn[nt];
        }
    }
    {
        float s1[2][4] = {{0.f,0.f,0.f,0.f},{0.f,0.f,0.f,0.f}};
        float s2[2][4] = {{0.f,0.f,0.f,0.f},{0.f,0.f,0.f,0.f}};
        #pragma unroll
        for (int nt = 0; nt < 3; nt++) {
            int n = n0 + nt * 16 + fr;
            float bv = b2[n];
            #pragma unroll
            for (int mt = 0; mt < 2; mt++)
                #pragma unroll
                for (int r = 0; r < 4; r++) {
                    float v = acc[mt][nt][r] + bv + bf2f(X1s[mt * 16 + quad * 4 + r][n]);
                    acc[mt][nt][r] = v;
                    s1[mt][r] += v;
                    s2[mt][r] += v * v;
                }
        }
        #pragma unroll
        for (int mt = 0; mt < 2; mt++)
            #pragma unroll
            for (int r = 0; r < 4; r++) {
                #pragma unroll
                for (int o = 1; o < 16; o <<= 1) {
                    s1[mt][r] += __shfl_xor(s1[mt][r], o, 64);
                    s2[mt][r] += __shfl_xor(s2[mt][r], o, 64);
                }
            }
        if (fr == 0) {
            #pragma unroll
            for (int mt = 0; mt < 2; mt++)
                #pragma unroll
                for (int r = 0; r < 4; r++) {
                    ssum[mt * 16 + quad * 4 + r][w] = s1[mt][r];
                    ssq [mt * 16 + quad * 4 + r][w] = s2[mt][r];
                }
        }
    }
    __syncthreads();
    {
        #pragma unroll
        for (int mt = 0; mt < 2; mt++) {
            float mu[4], rs[4];
            #pragma unroll
            for (int r = 0; r < 4; r++) {
                int row = mt * 16 + quad * 4 + r;
                float u1 = 0.f, u2 = 0.f;
                #pragma unroll
                for (int q = 0; q < 8; q++) { u1 += ssum[row][q]; u2 += ssq[row][q]; }
                mu[r] = u1 * (1.0f / EE);
                float var = u2 * (1.0f / EE) - mu[r] * mu[r];
                rs[r] = rsqrtf(var + 1e-5f);
            }
            #pragma unroll
            for (int nt = 0; nt < 3; nt++) {
                int n = n0 + nt * 16 + fr;
                float gv = g2[n], bev = be2[n];
                #pragma unroll
                for (int r = 0; r < 4; r++)
                    out[(size_t)(m0 + mt * 16 + quad * 4 + r) * EE + n] =
                        (acc[mt][nt][r] - mu[r]) * rs[r] * gv + bev;
            }
        }
    }
}

extern "C" void kernel_launch(void* const* d_in, const int* in_sizes, int n_in,
                              void* d_out, int out_size, void* d_ws, size_t ws_size,
                              hipStream_t stream) {
    (void)in_sizes; (void)n_in; (void)out_size; (void)ws_size;
    const float* x   = (const float*)d_in[0];
    const float* Wq  = (const float*)d_in[1];
    const float* Wo  = (const float*)d_in[2];
    const float* bo  = (const float*)d_in[3];
    const float* W1  = (const float*)d_in[4];
    const float* b1  = (const float*)d_in[5];
    const float* W2  = (const float*)d_in[6];
    const float* b2  = (const float*)d_in[7];
    const float* g1  = (const float*)d_in[8];
    const float* be1 = (const float*)d_in[9];
    const float* g2  = (const float*)d_in[10];
    const float* be2 = (const float*)d_in[11];
    float* out = (float*)d_out;

    float* ws = (float*)d_ws;
    const size_t SZ = (size_t)MM * EE;    // 3,145,728 elems / region (12.6 MB fp32)
    float* S1 = ws + SZ;                   // qbf + qbfT (bf16, fills region exactly)
    float* S2 = ws + 2 * SZ;               // catb (bf16)
    float* S3 = ws + 3 * SZ;               // xbf + weight bf16 copies

    unsigned short* qbf  = (unsigned short*)S1;
    unsigned short* qbfT = qbf + (size_t)BB * HH * TT * DD;   // AFTER all of qbf!
    unsigned short* catb = (unsigned short*)S2;
    unsigned short* xbf  = (unsigned short*)S3;
    unsigned short* wqb  = xbf + SZ;
    unsigned short* wob  = wqb + (size_t)EE * EE;
    unsigned short* w1b  = wob + (size_t)EE * EE;
    unsigned short* w2b  = w1b + (size_t)EE * EE;

    k_cvt<<<dim3(3072 + 4 * 144), dim3(256), 0, stream>>>(x, Wq, Wo, W1, W2,
                                                          xbf, wqb, wob, w1b, w2b);
    k_qgemm<<<dim3(MM / 32, 2), dim3(256), 0, stream>>>(xbf, wqb, qbf, qbfT);
    k_attn<<<dim3(768), dim3(256), 0, stream>>>(qbf, qbfT, catb);
    k_ffn<<<dim3(MM / 32), dim3(512), 0, stream>>>(catb, wob, bo, x, g1, be1,
                                                   w1b, b1, w2b, b2, g2, be2, out);
}

// Round 19
// 176.308 us; speedup vs baseline: 1.1973x; 1.0343x over previous
//
#include <hip/hip_runtime.h>
#include <math.h>

#define BB 4
#define TT 2048
#define EE 384
#define HH 6
#define DD 64
#define MM (BB*TT)   // 8192 tokens

typedef __attribute__((ext_vector_type(8))) short bf16x8;
typedef __attribute__((ext_vector_type(4))) float f32x4;

__device__ __forceinline__ unsigned short f2bf(float f) {
    unsigned int u = __float_as_uint(f);
    u = (u + 0x7FFFu + ((u >> 16) & 1u)) >> 16;   // RNE
    return (unsigned short)u;
}
__device__ __forceinline__ float bf2f(unsigned short u) {
    return __uint_as_float(((unsigned int)u) << 16);
}
__device__ __forceinline__ unsigned int pk2(float a, float b) {
    return (unsigned int)f2bf(a) | ((unsigned int)f2bf(b) << 16);
}

// ------------- fp32 -> bf16 conversion: WEIGHTS ONLY (4 x 144 blocks) ----------------
// (x conversion folded into k_qgemm's LDS staging -- same RNE, bit-identical values)
__global__ __launch_bounds__(256) void k_cvt(const float* __restrict__ wq,
                                             const float* __restrict__ wo,
                                             const float* __restrict__ w1,
                                             const float* __restrict__ w2,
                                             unsigned short* __restrict__ wqb,
                                             unsigned short* __restrict__ wob,
                                             unsigned short* __restrict__ w1b,
                                             unsigned short* __restrict__ w2b)
{
    int wi = blockIdx.x / 144, off = (blockIdx.x % 144) * 256;
    const float* s4[4] = {wq, wo, w1, w2};
    unsigned short* d4[4] = {wqb, wob, w1b, w2b};
    const float* src = s4[wi]; unsigned short* dst = d4[wi];
    int i = off + threadIdx.x;
    float4 v = ((const float4*)src)[i];
    uint2 o; o.x = pk2(v.x, v.y); o.y = pk2(v.z, v.w);
    ((uint2*)dst)[i] = o;
}

// ------------- q-GEMM: fp32 x staged+converted in LDS, W prefetch, fused qbfT --------
// 32 rows/block, wave 32m x 48n (2x3 -- the register-prefetch-surviving shape).
// A-tile: one coalesced fp32 pass -> bf16 LDS (pad 396: 6*fr mod 32 = 16 distinct even
// banks, b128 overlap <= 2-way = free). Epilogue unchanged from R18 (qbf + LDS-
// transposed qbfT, coalesced).
__global__ __launch_bounds__(256, 2) void k_qgemm(const float* __restrict__ x,
                                                  const unsigned short* __restrict__ W,
                                                  unsigned short* __restrict__ qbf,
                                                  unsigned short* __restrict__ qbfT)
{
    __shared__ unsigned short Xs[32][396];
    __shared__ unsigned short Ts[32][200];
    const int tid = threadIdx.x;
    const int w = tid >> 6, lane = tid & 63;
    const int fr = lane & 15, quad = lane >> 4;
    const int m0 = blockIdx.x * 32;
    const int n0 = blockIdx.y * 192 + w * 48;
    const unsigned short* Wp = W + (size_t)(n0 + fr) * EE + quad * 8;

    // ---- stage + convert A tile (32 x 384) ----
    {
        const float* xp = x + (size_t)m0 * EE;
        #pragma unroll
        for (int it = 0; it < 12; it++) {
            int idx = it * 1024 + tid * 4;
            int row = idx / EE, col = idx % EE;
            float4 v = *(const float4*)(xp + idx);
            uint2 o; o.x = pk2(v.x, v.y); o.y = pk2(v.z, v.w);
            *(uint2*)&Xs[row][col] = o;
        }
    }

    f32x4 acc[2][3];
    bf16x8 bc[3], bn[3];
    #pragma unroll
    for (int mt = 0; mt < 2; mt++)
        #pragma unroll
        for (int nt = 0; nt < 3; nt++) acc[mt][nt] = (f32x4){0.f, 0.f, 0.f, 0.f};
    #pragma unroll
    for (int nt = 0; nt < 3; nt++) bc[nt] = *(const bf16x8*)(Wp + (size_t)nt * 16 * EE);
    __syncthreads();   // Xs visible

    #pragma unroll
    for (int k0 = 0; k0 < 12; k0++) {
        if (k0 < 11) {
            #pragma unroll
            for (int nt = 0; nt < 3; nt++)
                bn[nt] = *(const bf16x8*)(Wp + (size_t)nt * 16 * EE + (k0 + 1) * 32);
        }
        bf16x8 a0 = *(const bf16x8*)&Xs[fr][k0 * 32 + quad * 8];
        bf16x8 a1 = *(const bf16x8*)&Xs[16 + fr][k0 * 32 + quad * 8];
        #pragma unroll
        for (int nt = 0; nt < 3; nt++) {
            acc[0][nt] = __builtin_amdgcn_mfma_f32_16x16x32_bf16(a0, bc[nt], acc[0][nt], 0, 0, 0);
            acc[1][nt] = __builtin_amdgcn_mfma_f32_16x16x32_bf16(a1, bc[nt], acc[1][nt], 0, 0, 0);
        }
        #pragma unroll
        for (int nt = 0; nt < 3; nt++) bc[nt] = bn[nt];
    }

    // epilogue: direct qbf writes + LDS stage for transposed qbfT
    const int bglob = m0 >> 11, t0 = m0 & 2047;
    #pragma unroll
    for (int nt = 0; nt < 3; nt++) {
        int nl = w * 48 + nt * 16 + fr;
        int n = blockIdx.y * 192 + nl;
        int h = n >> 6, d = n & 63;
        #pragma unroll
        for (int mt = 0; mt < 2; mt++)
            #pragma unroll
            for (int r = 0; r < 4; r++) {
                int ml = mt * 16 + quad * 4 + r;
                unsigned short bf = f2bf(acc[mt][nt][r]);
                qbf[((size_t)(bglob * HH + h) * TT + t0 + ml) * DD + d] = bf;
                Ts[ml][nl] = bf;
            }
    }
    __syncthreads();
    if (tid < 192) {
        int nl = tid;
        int n = blockIdx.y * 192 + nl;
        int h = n >> 6, d = n & 63;
        unsigned short tmp[32];
        #pragma unroll
        for (int i = 0; i < 32; i++) tmp[i] = Ts[i][nl];
        unsigned short* dst = qbfT + ((size_t)(bglob * HH + h) * DD + d) * TT + t0;
        *(uint4*)(dst)      = *(const uint4*)&tmp[0];
        *(uint4*)(dst + 8)  = *(const uint4*)&tmp[8];
        *(uint4*)(dst + 16) = *(const uint4*)&tmp[16];
        *(uint4*)(dst + 24) = *(const uint4*)&tmp[24];
    }
}

// ------------- MFMA flash attention: XCD swizzle + K/V LDS double-buffer (R17) -------
__global__ __launch_bounds__(256, 4) void k_attn(const unsigned short* __restrict__ qbf,
                                                 const unsigned short* __restrict__ qbfT,
                                                 unsigned short* __restrict__ cat)
{
    __shared__ unsigned short Qs[32][72];
    __shared__ unsigned short Ks[2][64][72];
    __shared__ unsigned short Vs[2][64][72];
    __shared__ unsigned short Ps[32][72];
    __shared__ float lsc[32];
    float (*Oc)[68] = (float(*)[68])&Ks[0][0][0];   // overlay (8704 B <= 9216 B)

    const int id = blockIdx.x;              // 0..767
    const int xcd = id & 7, j = id >> 3;
    const int bh = xcd * 3 + (j % 3);       // XCD-affine: 3 heads per XCD
    const int p = j / 3;                    // 0..31
    const int bb = bh / HH, hh = bh % HH;
    const int tid = threadIdx.x;
    const int w = tid >> 6, lane = tid & 63;
    const int qhalf = w & 1, keyhalf = w >> 1;
    const int fr = lane & 15, quad = lane >> 4;
    const int fc = quad * 8;
    const unsigned short* qb  = qbf  + (size_t)bh * TT * DD;
    const unsigned short* qtb = qbfT + (size_t)bh * DD * TT;
    const int lr = tid >> 2, lc = (tid & 3) * 16;
    const int qr = tid >> 3, qc = (tid & 7) * 8;

    #pragma unroll 1
    for (int ph = 0; ph < 2; ph++) {
        const int tile = ph ? (63 - p) : p;
        const int m0 = tile * 32;
        const int nkt = (tile >> 1) + 1;

        uint4 kr0, kr1, vr0, vr1;
        {
            const unsigned short* kp = qb + (size_t)lr * DD + lc;
            kr0 = *(const uint4*)(kp);
            kr1 = *(const uint4*)(kp + 8);
            const unsigned short* vp = qtb + (size_t)lr * TT + lc;
            vr0 = *(const uint4*)(vp);
            vr1 = *(const uint4*)(vp + 8);
        }

        __syncthreads();   // prev phase fully done (incl. Oc-overlay reads)
        {
            const unsigned short* qp = qb + (size_t)(m0 + qr) * DD + qc;
            *(uint4*)&Qs[qr][qc] = *(const uint4*)(qp);
        }
        *(uint4*)&Ks[0][lr][lc]     = kr0;
        *(uint4*)&Ks[0][lr][lc + 8] = kr1;
        *(uint4*)&Vs[0][lr][lc]     = vr0;
        *(uint4*)&Vs[0][lr][lc + 8] = vr1;
        __syncthreads();   // Qs + buf0 visible
        const bf16x8 qA0 = *(const bf16x8*)&Qs[qhalf * 16 + fr][fc];
        const bf16x8 qA1 = *(const bf16x8*)&Qs[qhalf * 16 + fr][fc + 32];

        f32x4 accO[4];
        #pragma unroll
        for (int dt = 0; dt < 4; dt++) accO[dt] = (f32x4){0.f, 0.f, 0.f, 0.f};
        float ls[4] = {0.f, 0.f, 0.f, 0.f};
        const int rowbase = m0 + qhalf * 16 + quad * 4;
        const int prow = qhalf * 16 + quad * 4;

        for (int kt = 0; kt < nkt; kt++) {
            const int cur = kt & 1;
            const int s0 = kt * 64;
            if (kt < nkt - 1) {
                const unsigned short* kp = qb + (size_t)(s0 + 64 + lr) * DD + lc;
                kr0 = *(const uint4*)(kp);
                kr1 = *(const uint4*)(kp + 8);
                const unsigned short* vp = qtb + (size_t)lr * TT + s0 + 64 + lc;
                vr0 = *(const uint4*)(vp);
                vr1 = *(const uint4*)(vp + 8);
            }

            f32x4 S[2];
            #pragma unroll
            for (int nt = 0; nt < 2; nt++) {
                f32x4 acc = (f32x4){0.f, 0.f, 0.f, 0.f};
                bf16x8 b0 = *(const bf16x8*)&Ks[cur][keyhalf * 32 + nt * 16 + fr][fc];
                acc = __builtin_amdgcn_mfma_f32_16x16x32_bf16(qA0, b0, acc, 0, 0, 0);
                bf16x8 b1 = *(const bf16x8*)&Ks[cur][keyhalf * 32 + nt * 16 + fr][fc + 32];
                acc = __builtin_amdgcn_mfma_f32_16x16x32_bf16(qA1, b1, acc, 0, 0, 0);
                S[nt] = acc;
            }

            #pragma unroll
            for (int nt = 0; nt < 2; nt++) {
                int jg = s0 + keyhalf * 32 + nt * 16 + fr;
                #pragma unroll
                for (int r = 0; r < 4; r++) {
                    float v = S[nt][r] * 0.125f;
                    float pv = (jg <= rowbase + r && v != 0.0f) ? __expf(v) : 0.0f;
                    ls[r] += pv;
                    Ps[prow + r][keyhalf * 32 + nt * 16 + fr] = f2bf(pv);
                }
            }

            bf16x8 pA = *(const bf16x8*)&Ps[qhalf * 16 + fr][keyhalf * 32 + fc];
            #pragma unroll
            for (int dt = 0; dt < 4; dt++) {
                bf16x8 v0 = *(const bf16x8*)&Vs[cur][dt * 16 + fr][keyhalf * 32 + fc];
                accO[dt] = __builtin_amdgcn_mfma_f32_16x16x32_bf16(pA, v0, accO[dt], 0, 0, 0);
            }

            if (kt < nkt - 1) {
                *(uint4*)&Ks[cur ^ 1][lr][lc]     = kr0;
                *(uint4*)&Ks[cur ^ 1][lr][lc + 8] = kr1;
                *(uint4*)&Vs[cur ^ 1][lr][lc]     = vr0;
                *(uint4*)&Vs[cur ^ 1][lr][lc + 8] = vr1;
                __syncthreads();   // single barrier per iteration
            }
        }

        __syncthreads();   // final-iter LDS reads complete before Oc-overlay write
        #pragma unroll
        for (int r = 0; r < 4; r++) {
            #pragma unroll
            for (int o = 1; o < 16; o <<= 1) ls[r] += __shfl_xor(ls[r], o, 64);
        }
        if (keyhalf == 1) {
            #pragma unroll
            for (int dt = 0; dt < 4; dt++)
                #pragma unroll
                for (int r = 0; r < 4; r++)
                    Oc[prow + r][dt * 16 + fr] = accO[dt][r];
            if (fr == 0) {
                #pragma unroll
                for (int r = 0; r < 4; r++) lsc[prow + r] = ls[r];
            }
        }
        __syncthreads();
        if (keyhalf == 0) {
            float lt[4];
            #pragma unroll
            for (int r = 0; r < 4; r++) lt[r] = ls[r] + lsc[prow + r];
            #pragma unroll
            for (int dt = 0; dt < 4; dt++) {
                #pragma unroll
                for (int r = 0; r < 4; r++) {
                    float o = accO[dt][r] + Oc[prow + r][dt * 16 + fr];
                    int t = rowbase + r;
                    cat[((size_t)bb * TT + t) * EE + hh * DD + dt * 16 + fr] =
                        f2bf(o / lt[r]);
                }
            }
        }
    }
}

// ------------- fused proj+LN1 + FFN1 + FFN2+LN2 (R15/R17 shape + early W prefetch) ---
// GEMM2's / GEMM3's first weight frags now load right after the previous GEMM's
// k-loop, so their cold-load latency overlaps the LN/epilogue VALU phase.
__global__ __launch_bounds__(512, 2) void k_ffn(const unsigned short* __restrict__ catb,
                                                const unsigned short* __restrict__ wob,
                                                const float* __restrict__ bo,
                                                const float* __restrict__ x,
                                                const float* __restrict__ g1,
                                                const float* __restrict__ be1,
                                                const unsigned short* __restrict__ w1b,
                                                const float* __restrict__ b1,
                                                const unsigned short* __restrict__ w2b,
                                                const float* __restrict__ b2,
                                                const float* __restrict__ g2,
                                                const float* __restrict__ be2,
                                                float* __restrict__ out)
{
    __shared__ unsigned short X1s[32][392];
    __shared__ unsigned short H1s[32][392];
    __shared__ float ssum[32][8];
    __shared__ float ssq[32][8];
    const int tid = threadIdx.x;
    const int w = tid >> 6, lane = tid & 63;
    const int fr = lane & 15, quad = lane >> 4;
    const int m0 = blockIdx.x * 32;
    const int n0 = w * 48;

    f32x4 acc[2][3];
    bf16x8 bc[3], bn[3];
    const unsigned short* Wp1 = w1b + (size_t)(n0 + fr) * EE + quad * 8;
    const unsigned short* Wp2 = w2b + (size_t)(n0 + fr) * EE + quad * 8;

    // ================= GEMM1: proj = catb @ Wo^T (2 m-tiles) =================
    {
        const unsigned short* Ap0 = catb + (size_t)(m0 + fr) * EE + quad * 8;
        const unsigned short* Ap1 = Ap0 + 16 * EE;
        const unsigned short* Wp = wob + (size_t)(n0 + fr) * EE + quad * 8;
        #pragma unroll
        for (int mt = 0; mt < 2; mt++)
            #pragma unroll
            for (int nt = 0; nt < 3; nt++) acc[mt][nt] = (f32x4){0.f, 0.f, 0.f, 0.f};
        #pragma unroll
        for (int nt = 0; nt < 3; nt++) bc[nt] = *(const bf16x8*)(Wp + (size_t)nt * 16 * EE);
        #pragma unroll
        for (int k0 = 0; k0 < 12; k0++) {
            if (k0 < 11) {
                #pragma unroll
                for (int nt = 0; nt < 3; nt++)
                    bn[nt] = *(const bf16x8*)(Wp + (size_t)nt * 16 * EE + (k0 + 1) * 32);
            }
            bf16x8 a0 = *(const bf16x8*)(Ap0 + k0 * 32);
            bf16x8 a1 = *(const bf16x8*)(Ap1 + k0 * 32);
            #pragma unroll
            for (int nt = 0; nt < 3; nt++) {
                acc[0][nt] = __builtin_amdgcn_mfma_f32_16x16x32_bf16(a0, bc[nt], acc[0][nt], 0, 0, 0);
                acc[1][nt] = __builtin_amdgcn_mfma_f32_16x16x32_bf16(a1, bc[nt], acc[1][nt], 0, 0, 0);
            }
            #pragma unroll
            for (int nt = 0; nt < 3; nt++) bc[nt] = bn[nt];
        }
    }
    // early prefetch of GEMM2's first weight frags (overlaps LN1 VALU)
    #pragma unroll
    for (int nt = 0; nt < 3; nt++) bc[nt] = *(const bf16x8*)(Wp1 + (size_t)nt * 16 * EE);
    // + bo + resid(x) -> LN1 stats
    {
        float s1[2][4] = {{0.f,0.f,0.f,0.f},{0.f,0.f,0.f,0.f}};
        float s2[2][4] = {{0.f,0.f,0.f,0.f},{0.f,0.f,0.f,0.f}};
        #pragma unroll
        for (int nt = 0; nt < 3; nt++) {
            int n = n0 + nt * 16 + fr;
            float bv = bo[n];
            #pragma unroll
            for (int mt = 0; mt < 2; mt++)
                #pragma unroll
                for (int r = 0; r < 4; r++) {
                    float v = acc[mt][nt][r] + bv
                            + x[(size_t)(m0 + mt * 16 + quad * 4 + r) * EE + n];
                    acc[mt][nt][r] = v;
                    s1[mt][r] += v;
                    s2[mt][r] += v * v;
                }
        }
        #pragma unroll
        for (int mt = 0; mt < 2; mt++)
            #pragma unroll
            for (int r = 0; r < 4; r++) {
                #pragma unroll
                for (int o = 1; o < 16; o <<= 1) {
                    s1[mt][r] += __shfl_xor(s1[mt][r], o, 64);
                    s2[mt][r] += __shfl_xor(s2[mt][r], o, 64);
                }
            }
        if (fr == 0) {
            #pragma unroll
            for (int mt = 0; mt < 2; mt++)
                #pragma unroll
                for (int r = 0; r < 4; r++) {
                    ssum[mt * 16 + quad * 4 + r][w] = s1[mt][r];
                    ssq [mt * 16 + quad * 4 + r][w] = s2[mt][r];
                }
        }
    }
    __syncthreads();
    {
        #pragma unroll
        for (int mt = 0; mt < 2; mt++) {
            float mu[4], rs[4];
            #pragma unroll
            for (int r = 0; r < 4; r++) {
                int row = mt * 16 + quad * 4 + r;
                float t1 = 0.f, t2 = 0.f;
                #pragma unroll
                for (int q = 0; q < 8; q++) { t1 += ssum[row][q]; t2 += ssq[row][q]; }
                mu[r] = t1 * (1.0f / EE);
                float var = t2 * (1.0f / EE) - mu[r] * mu[r];
                rs[r] = rsqrtf(var + 1e-5f);
            }
            #pragma unroll
            for (int nt = 0; nt < 3; nt++) {
                int n = n0 + nt * 16 + fr;
                float gv = g1[n], bev = be1[n];
                #pragma unroll
                for (int r = 0; r < 4; r++) {
                    float v = (acc[mt][nt][r] - mu[r]) * rs[r] * gv + bev;
                    X1s[mt * 16 + quad * 4 + r][n] = f2bf(v);
                }
            }
        }
    }
    __syncthreads();

    // ================= GEMM2: h1 = relu(x1 @ W1^T + b1) =================
    {
        #pragma unroll
        for (int mt = 0; mt < 2; mt++)
            #pragma unroll
            for (int nt = 0; nt < 3; nt++) acc[mt][nt] = (f32x4){0.f, 0.f, 0.f, 0.f};
        #pragma unroll
        for (int k0 = 0; k0 < 12; k0++) {
            if (k0 < 11) {
                #pragma unroll
                for (int nt = 0; nt < 3; nt++)
                    bn[nt] = *(const bf16x8*)(Wp1 + (size_t)nt * 16 * EE + (k0 + 1) * 32);
            }
            bf16x8 a0 = *(const bf16x8*)&X1s[fr][k0 * 32 + quad * 8];
            bf16x8 a1 = *(const bf16x8*)&X1s[16 + fr][k0 * 32 + quad * 8];
            #pragma unroll
            for (int nt = 0; nt < 3; nt++) {
                acc[0][nt] = __builtin_amdgcn_mfma_f32_16x16x32_bf16(a0, bc[nt], acc[0][nt], 0, 0, 0);
                acc[1][nt] = __builtin_amdgcn_mfma_f32_16x16x32_bf16(a1, bc[nt], acc[1][nt], 0, 0, 0);
            }
            #pragma unroll
            for (int nt = 0; nt < 3; nt++) bc[nt] = bn[nt];
        }
        // early prefetch of GEMM3's first weight frags (overlaps relu/store VALU)
        #pragma unroll
        for (int nt = 0; nt < 3; nt++) bc[nt] = *(const bf16x8*)(Wp2 + (size_t)nt * 16 * EE);
        #pragma unroll
        for (int nt = 0; nt < 3; nt++) {
            int n = n0 + nt * 16 + fr;
            float bv = b1[n];
            #pragma unroll
            for (int mt = 0; mt < 2; mt++)
                #pragma unroll
                for (int r = 0; r < 4; r++)
                    H1s[mt * 16 + quad * 4 + r][n] = f2bf(fmaxf(acc[mt][nt][r] + bv, 0.0f));
        }
    }
    __syncthreads();

    // ================= GEMM3: ff = h1 @ W2^T + b2; LN2(x1 + ff) -> out =================
    {
        #pragma unroll
        for (int mt = 0; mt < 2; mt++)
            #pragma unroll
            for (int nt = 0; nt < 3; nt++) acc[mt][nt] = (f32x4){0.f, 0.f, 0.f, 0.f};
        #pragma unroll
        for (int k0 = 0; k0 < 12; k0++) {
            if (k0 < 11) {
                #pragma unroll
                for (int nt = 0; nt < 3; nt++)
                    bn[nt] = *(const bf16x8*)(Wp2 + (size_t)nt * 16 * EE + (k0 + 1) * 32);
            }
            bf16x8 a0 = *(const bf16x8*)&H1s[fr][k0 * 32 + quad * 8];
            bf16x8 a1 = *(const bf16x8*)&H1s[16 + fr][k0 * 32 + quad * 8];
            #pragma unroll
            for (int nt = 0; nt < 3; nt++) {
                acc[0][nt] = __builtin_amdgcn_mfma_f32_16x16x32_bf16(a0, bc[nt], acc[0][nt], 0, 0, 0);
                acc[1][nt] = __builtin_amdgcn_mfma_f32_16x16x32_bf16(a1, bc[nt], acc[1][nt], 0, 0, 0);
            }
            #pragma unroll
            for (int nt = 0; nt < 3; nt++) bc[nt] = bn[nt];
        }
    }
    {
        float s1[2][4] = {{0.f,0.f,0.f,0.f},{0.f,0.f,0.f,0.f}};
        float s2[2][4] = {{0.f,0.f,0.f,0.f},{0.f,0.f,0.f,0.f}};
        #pragma unroll
        for (int nt = 0; nt < 3; nt++) {
            int n = n0 + nt * 16 + fr;
            float bv = b2[n];
            #pragma unroll
            for (int mt = 0; mt < 2; mt++)
                #pragma unroll
                for (int r = 0; r < 4; r++) {
                    float v = acc[mt][nt][r] + bv + bf2f(X1s[mt * 16 + quad * 4 + r][n]);
                    acc[mt][nt][r] = v;
                    s1[mt][r] += v;
                    s2[mt][r] += v * v;
                }
        }
        #pragma unroll
        for (int mt = 0; mt < 2; mt++)
            #pragma unroll
            for (int r = 0; r < 4; r++) {
                #pragma unroll
                for (int o = 1; o < 16; o <<= 1) {
                    s1[mt][r] += __shfl_xor(s1[mt][r], o, 64);
                    s2[mt][r] += __shfl_xor(s2[mt][r], o, 64);
                }
            }
        if (fr == 0) {
            #pragma unroll
            for (int mt = 0; mt < 2; mt++)
                #pragma unroll
                for (int r = 0; r < 4; r++) {
                    ssum[mt * 16 + quad * 4 + r][w] = s1[mt][r];
                    ssq [mt * 16 + quad * 4 + r][w] = s2[mt][r];
                }
        }
    }
    __syncthreads();
    {
        #pragma unroll
        for (int mt = 0; mt < 2; mt++) {
            float mu[4], rs[4];
            #pragma unroll
            for (int r = 0; r < 4; r++) {
                int row = mt * 16 + quad * 4 + r;
                float u1 = 0.f, u2 = 0.f;
                #pragma unroll
                for (int q = 0; q < 8; q++) { u1 += ssum[row][q]; u2 += ssq[row][q]; }
                mu[r] = u1 * (1.0f / EE);
                float var = u2 * (1.0f / EE) - mu[r] * mu[r];
                rs[r] = rsqrtf(var + 1e-5f);
            }
            #pragma unroll
            for (int nt = 0; nt < 3; nt++) {
                int n = n0 + nt * 16 + fr;
                float gv = g2[n], bev = be2[n];
                #pragma unroll
                for (int r = 0; r < 4; r++)
                    out[(size_t)(m0 + mt * 16 + quad * 4 + r) * EE + n] =
                        (acc[mt][nt][r] - mu[r]) * rs[r] * gv + bev;
            }
        }
    }
}

extern "C" void kernel_launch(void* const* d_in, const int* in_sizes, int n_in,
                              void* d_out, int out_size, void* d_ws, size_t ws_size,
                              hipStream_t stream) {
    (void)in_sizes; (void)n_in; (void)out_size; (void)ws_size;
    const float* x   = (const float*)d_in[0];
    const float* Wq  = (const float*)d_in[1];
    const float* Wo  = (const float*)d_in[2];
    const float* bo  = (const float*)d_in[3];
    const float* W1  = (const float*)d_in[4];
    const float* b1  = (const float*)d_in[5];
    const float* W2  = (const float*)d_in[6];
    const float* b2  = (const float*)d_in[7];
    const float* g1  = (const float*)d_in[8];
    const float* be1 = (const float*)d_in[9];
    const float* g2  = (const float*)d_in[10];
    const float* be2 = (const float*)d_in[11];
    float* out = (float*)d_out;

    float* ws = (float*)d_ws;
    const size_t SZ = (size_t)MM * EE;    // 3,145,728 elems / region (12.6 MB fp32)
    float* S1 = ws + SZ;                   // qbf + qbfT (bf16, fills region exactly)
    float* S2 = ws + 2 * SZ;               // catb (bf16)
    float* S3 = ws + 3 * SZ;               // weight bf16 copies

    unsigned short* qbf  = (unsigned short*)S1;
    unsigned short* qbfT = qbf + (size_t)BB * HH * TT * DD;   // AFTER all of qbf!
    unsigned short* catb = (unsigned short*)S2;
    unsigned short* wqb  = (unsigned short*)S3;
    unsigned short* wob  = wqb + (size_t)EE * EE;
    unsigned short* w1b  = wob + (size_t)EE * EE;
    unsigned short* w2b  = w1b + (size_t)EE * EE;

    k_cvt<<<dim3(4 * 144), dim3(256), 0, stream>>>(Wq, Wo, W1, W2, wqb, wob, w1b, w2b);
    k_qgemm<<<dim3(MM / 32, 2), dim3(256), 0, stream>>>(x, wqb, qbf, qbfT);
    k_attn<<<dim3(768), dim3(256), 0, stream>>>(qbf, qbfT, catb);
    k_ffn<<<dim3(MM / 32), dim3(512), 0, stream>>>(catb, wob, bo, x, g1, be1,
                                                   w1b, b1, w2b, b2, g2, be2, out);
}